// Round 3
// baseline (243.608 us; speedup 1.0000x reference)
//
#include <hip/hip_runtime.h>
#include <math.h>

#define BB 4
#define NN 1024
#define CC 384
#define KK 10
#define NKK (NN*KK)

typedef __attribute__((ext_vector_type(8))) short short8v;
typedef __attribute__((ext_vector_type(8))) unsigned short ushort8v;
typedef __attribute__((ext_vector_type(4))) float f32x4;

__device__ __forceinline__ float wave_sum(float v) {
  #pragma unroll
  for (int off = 32; off > 0; off >>= 1) v += __shfl_xor(v, off, 64);
  return v;
}

__device__ __forceinline__ unsigned short f2bf(float x) {
  unsigned int b = __float_as_uint(x);
  return (unsigned short)((b + 0x7fffu + ((b >> 16) & 1u)) >> 16);  // RNE
}

// ---------------- q -> bf16 bits ----------------
__global__ void cvt_bf16_kernel(const float* __restrict__ in, unsigned short* __restrict__ out) {
  int i = (blockIdx.x * 256 + threadIdx.x) * 4;
  float4 v = *reinterpret_cast<const float4*>(in + i);
  out[i + 0] = f2bf(v.x); out[i + 1] = f2bf(v.y);
  out[i + 2] = f2bf(v.z); out[i + 3] = f2bf(v.w);
}

// ---------------- bias_uv = [0 | c1], bias_pb = [0 | bk] ----------------
__global__ void biasprep_kernel(const float* __restrict__ W1, const float* __restrict__ b1,
                                const float* __restrict__ bv, const float* __restrict__ bk,
                                float* __restrict__ bias_uv, float* __restrict__ bias_pb) {
  int j = blockIdx.x * 256 + threadIdx.x;
  if (j >= 2 * CC) return;
  if (j < CC) { bias_uv[j] = 0.f; bias_pb[j] = 0.f; }
  else {
    int c = j - CC;
    float s = b1[c];
    for (int i = 0; i < CC; ++i) s += bv[i] * W1[i * CC + c];
    bias_uv[j] = s;          // c1
    bias_pb[j] = bk[c];
  }
}

// ---------------- Bcat_uv[r][0:384]=sum_p M1p ; [384:768]=W1_bot[r] ----------------
__global__ void pack_uv_kernel(const float* __restrict__ M1p, const float* __restrict__ W1,
                               float* __restrict__ Bcat_uv) {
  int idx = blockIdx.x * 256 + threadIdx.x;   // 384*768
  int r = idx / (2 * CC), j = idx % (2 * CC);
  float v;
  if (j < CC) {
    float s = 0.f;
    #pragma unroll
    for (int p = 0; p < 8; ++p) s += M1p[(size_t)p * CC * CC + r * CC + j];
    v = s;
  } else {
    v = W1[(size_t)(CC + r) * CC + (j - CC)];
  }
  Bcat_uv[(size_t)r * 2 * CC + j] = v;
}

// ---------------- Wt_pb[n][k] (bf16): n<384 -> Wk_top[k][n]; else Wkdiff ----------------
__global__ void pack_pb_kernel(const float* __restrict__ Wk, unsigned short* __restrict__ Wt) {
  int idx = blockIdx.x * 256 + threadIdx.x;   // 768*384
  int n = idx / CC, k = idx % CC;
  float v;
  if (n < CC) v = Wk[(size_t)k * CC + n];
  else        v = Wk[(size_t)CC * CC + k * CC + (n - CC)] - Wk[(size_t)k * CC + (n - CC)];
  Wt[(size_t)n * CC + k] = f2bf(v);
}

// ---------------- f32 GEMM 128x128 tile, 8x8/thread, optional split-K ----------------
__global__ __launch_bounds__(256) void gemm128_kernel(
    const float* __restrict__ A, const float* __restrict__ Bm,
    float* __restrict__ Cm, const float* __restrict__ bias,
    int M, int Ncol, int Kd, int ksplit) {
  __shared__ float As[16][132];   // padded: 2-way max on transposed stores
  __shared__ float Bs[16][128];
  int tid = threadIdx.x;
  int tx = tid & 15, ty = tid >> 4;
  int row0 = blockIdx.y * 128, col0 = blockIdx.x * 128;
  int klen = Kd / ksplit;
  int k0 = blockIdx.z * klen;
  float acc[8][8] = {};
  int arow = tid >> 2, akc = (tid & 3) << 2;
  int brow = tid >> 5, bcol = (tid & 31) << 2;
  for (int kt = k0; kt < k0 + klen; kt += 16) {
    #pragma unroll
    for (int h = 0; h < 2; ++h) {
      int r = arow + 64 * h;
      float4 av = *reinterpret_cast<const float4*>(A + (size_t)(row0 + r) * Kd + kt + akc);
      As[akc + 0][r] = av.x; As[akc + 1][r] = av.y;
      As[akc + 2][r] = av.z; As[akc + 3][r] = av.w;
    }
    #pragma unroll
    for (int h = 0; h < 2; ++h) {
      int r = brow + 8 * h;
      float4 bv4 = *reinterpret_cast<const float4*>(Bm + (size_t)(kt + r) * Ncol + col0 + bcol);
      *reinterpret_cast<float4*>(&Bs[r][bcol]) = bv4;
    }
    __syncthreads();
    #pragma unroll
    for (int kk = 0; kk < 16; ++kk) {
      float4 a0 = *reinterpret_cast<const float4*>(&As[kk][ty << 2]);
      float4 a1 = *reinterpret_cast<const float4*>(&As[kk][64 + (ty << 2)]);
      float4 b0 = *reinterpret_cast<const float4*>(&Bs[kk][tx << 2]);
      float4 b1 = *reinterpret_cast<const float4*>(&Bs[kk][64 + (tx << 2)]);
      float av_[8] = {a0.x, a0.y, a0.z, a0.w, a1.x, a1.y, a1.z, a1.w};
      float bv_[8] = {b0.x, b0.y, b0.z, b0.w, b1.x, b1.y, b1.z, b1.w};
      #pragma unroll
      for (int i = 0; i < 8; ++i) {
        #pragma unroll
        for (int j = 0; j < 8; ++j) acc[i][j] += av_[i] * bv_[j];
      }
    }
    __syncthreads();
  }
  float* Cz = Cm + (size_t)blockIdx.z * M * Ncol;
  #pragma unroll
  for (int i = 0; i < 8; ++i) {
    int row = row0 + (ty << 2) + (i & 3) + ((i & 4) << 4);
    #pragma unroll
    for (int h = 0; h < 2; ++h) {
      int col = col0 + 64 * h + (tx << 2);
      float4 r;
      r.x = acc[i][4 * h + 0]; r.y = acc[i][4 * h + 1];
      r.z = acc[i][4 * h + 2]; r.w = acc[i][4 * h + 3];
      if (bias) { r.x += bias[col]; r.y += bias[col + 1]; r.z += bias[col + 2]; r.w += bias[col + 3]; }
      *reinterpret_cast<float4*>(Cz + (size_t)row * Ncol + col) = r;
    }
  }
}

// ---------------- bf16 MFMA GEMM: C[4096,768] = qb @ Wt^T (+bias) ----------------
// A_lds/B_lds: [128 rows][32 k] bf16, slot-XOR swizzle on both write and read.
__global__ __launch_bounds__(256) void gemm_pb_kernel(
    const unsigned short* __restrict__ Aq, const unsigned short* __restrict__ Wt,
    float* __restrict__ Cm, const float* __restrict__ bias) {
  __shared__ unsigned short Al[128 * 32];
  __shared__ unsigned short Bl[128 * 32];
  int tid = threadIdx.x;
  int lane = tid & 63, w = tid >> 6;
  int m0 = blockIdx.y * 128, n0 = blockIdx.x * 128;
  f32x4 acc[4][4];
  #pragma unroll
  for (int i = 0; i < 4; ++i)
    #pragma unroll
    for (int j = 0; j < 4; ++j) acc[i][j] = (f32x4){0.f, 0.f, 0.f, 0.f};
  int rl = lane & 15, kg = lane >> 4;
  for (int k0 = 0; k0 < CC; k0 += 32) {
    #pragma unroll
    for (int j = 0; j < 2; ++j) {
      int id = tid + 256 * j;
      int r = id >> 2, s = id & 3;
      int sw = s ^ (r & 3);
      ushort8v va = *reinterpret_cast<const ushort8v*>(Aq + (size_t)(m0 + r) * CC + k0 + s * 8);
      *reinterpret_cast<ushort8v*>(Al + r * 32 + sw * 8) = va;
      ushort8v vb = *reinterpret_cast<const ushort8v*>(Wt + (size_t)(n0 + r) * CC + k0 + s * 8);
      *reinterpret_cast<ushort8v*>(Bl + r * 32 + sw * 8) = vb;
    }
    __syncthreads();
    short8v af[4], bf[4];
    #pragma unroll
    for (int f = 0; f < 4; ++f) {
      int ar = (w & 1) * 64 + f * 16 + rl;
      af[f] = *reinterpret_cast<const short8v*>(Al + ar * 32 + (kg ^ (ar & 3)) * 8);
      int br = (w >> 1) * 64 + f * 16 + rl;
      bf[f] = *reinterpret_cast<const short8v*>(Bl + br * 32 + (kg ^ (br & 3)) * 8);
    }
    #pragma unroll
    for (int i = 0; i < 4; ++i) {
      #pragma unroll
      for (int j = 0; j < 4; ++j)
        acc[i][j] = __builtin_amdgcn_mfma_f32_16x16x32_bf16(af[i], bf[j], acc[i][j], 0, 0, 0);
    }
    __syncthreads();
  }
  // C/D layout: col = lane&15, row = (lane>>4)*4 + reg
  #pragma unroll
  for (int i = 0; i < 4; ++i) {
    #pragma unroll
    for (int j = 0; j < 4; ++j) {
      int col = n0 + (w >> 1) * 64 + j * 16 + rl;
      float bcol_v = bias[col];
      #pragma unroll
      for (int r = 0; r < 4; ++r) {
        int row = m0 + (w & 1) * 64 + i * 16 + kg * 4 + r;
        Cm[(size_t)row * (2 * CC) + col] = acc[i][j][r] + bcol_v;
      }
    }
  }
}

// ---------------- KNN: one wave per query; |m|^2 precomputed in LDS ----------------
__global__ __launch_bounds__(256) void knn_kernel(const float* __restrict__ q_pos,
                                                  int* __restrict__ idx_out) {
  __shared__ float sx[NN], sy[NN], sz[NN];
  __shared__ double sq[NN];
  int b = blockIdx.y;
  int t = threadIdx.x;
  const float* qp = q_pos + (size_t)b * NN * 3;
  for (int i = t; i < NN; i += 256) {
    float x = qp[i * 3 + 0], y = qp[i * 3 + 1], z = qp[i * 3 + 2];
    sx[i] = x; sy[i] = y; sz[i] = z;
    sq[i] = (double)x * x + (double)y * y + (double)z * z;
  }
  __syncthreads();
  int wave = t >> 6, lane = t & 63;
  int n = blockIdx.x * 4 + wave;
  double px = (double)sx[n], py = (double)sy[n], pz = (double)sz[n];
  double sp = px * px + py * py + pz * pz;
  double bd[KK]; int bi[KK];
  #pragma unroll
  for (int s = 0; s < KK; ++s) { bd[s] = 1e300; bi[s] = -1; }
  #pragma unroll 4
  for (int j = 0; j < 16; ++j) {
    int m = lane + (j << 6);
    double dot = px * sx[m] + py * sy[m] + pz * sz[m];
    double d = sp + sq[m] - 2.0 * dot;
    if (d < 0.0) d = 0.0;
    if (d < bd[KK - 1]) {
      bd[KK - 1] = d; bi[KK - 1] = m;
      #pragma unroll
      for (int s = KK - 1; s >= 1; --s) {
        if (bd[s] < bd[s - 1]) {
          double td = bd[s]; bd[s] = bd[s - 1]; bd[s - 1] = td;
          int ti = bi[s]; bi[s] = bi[s - 1]; bi[s - 1] = ti;
        }
      }
    }
  }
  int* op = idx_out + ((size_t)b * NN + n) * KK;
  for (int s = 0; s < KK; ++s) {
    double d = bd[0]; int i = bi[0];
    #pragma unroll
    for (int off = 32; off > 0; off >>= 1) {
      double od = __shfl_xor(d, off, 64);
      int oi = __shfl_xor(i, off, 64);
      if (od < d || (od == d && oi < i)) { d = od; i = oi; }
    }
    if (bi[0] == i) {
      #pragma unroll
      for (int u = 0; u < KK - 1; ++u) { bd[u] = bd[u + 1]; bi[u] = bi[u + 1]; }
      bd[KK - 1] = 1e300; bi[KK - 1] = -1;
    }
    if (lane == 0) op[s] = i;
  }
}

// -------- fused MLP per (b,n): loop k; h=U[idx]+V -> LN -> gelu -> tanh(h@W2) --------
__global__ __launch_bounds__(64) void mlp_kernel(
    const float* __restrict__ Cat_uv, const float* __restrict__ lng, const float* __restrict__ lnb,
    const float* __restrict__ W2, const int* __restrict__ idxk, const float* __restrict__ q_pos,
    float* __restrict__ shp) {
  int bn = blockIdx.x;
  int b = bn >> 10;
  int lane = threadIdx.x;
  __shared__ int s_nb[KK];
  __shared__ float s_scale[3], s_lvp[KK][3];
  if (lane < KK) s_nb[lane] = idxk[(size_t)bn * KK + lane];
  __syncthreads();
  if (lane < 3) {
    float mx = -1e30f, mn = 1e30f;
    #pragma unroll
    for (int k2 = 0; k2 < KK; ++k2) {
      float v = q_pos[((size_t)b * NN + s_nb[k2]) * 3 + lane];
      mx = fmaxf(mx, v); mn = fminf(mn, v);
      s_lvp[k2][lane] = v;
    }
    s_scale[lane] = (mx - mn) * 0.5f;
  }
  __syncthreads();
  float Vv[6], lg[6], lb[6], w2a[6], w2b[6], w2c[6];
  const float* Vrow = Cat_uv + (size_t)bn * (2 * CC) + CC;
  #pragma unroll
  for (int i = 0; i < 6; ++i) {
    int c = lane + (i << 6);
    Vv[i] = Vrow[c];
    lg[i] = lng[c]; lb[i] = lnb[c];
    w2a[i] = W2[c * 3 + 0]; w2b[i] = W2[c * 3 + 1]; w2c[i] = W2[c * 3 + 2];
  }
  for (int k = 0; k < KK; ++k) {
    const float* Urow = Cat_uv + ((size_t)b * NN + s_nb[k]) * (2 * CC);
    float h[6];
    float ls = 0.f;
    #pragma unroll
    for (int i = 0; i < 6; ++i) {
      h[i] = Urow[lane + (i << 6)] + Vv[i];
      ls += h[i];
    }
    ls = wave_sum(ls);
    float mu = ls * (1.0f / CC);
    float lv = 0.f;
    #pragma unroll
    for (int i = 0; i < 6; ++i) { float d = h[i] - mu; lv += d * d; }
    lv = wave_sum(lv);
    float rstd = 1.0f / sqrtf(lv * (1.0f / CC) + 1e-5f);
    float o0 = 0.f, o1 = 0.f, o2 = 0.f;
    #pragma unroll
    for (int i = 0; i < 6; ++i) {
      float x = (h[i] - mu) * rstd * lg[i] + lb[i];
      float g = 0.5f * x * (1.0f + erff(x * 0.70710678118654752440f));
      o0 += g * w2a[i]; o1 += g * w2b[i]; o2 += g * w2c[i];
    }
    o0 = wave_sum(o0); o1 = wave_sum(o1); o2 = wave_sum(o2);
    if (lane == 0) {
      float* sp = shp + ((size_t)bn * KK + k) * 3;
      sp[0] = s_lvp[k][0] + tanhf(o0) * s_scale[0];
      sp[1] = s_lvp[k][1] + tanhf(o1) * s_scale[1];
      sp[2] = s_lvp[k][2] + tanhf(o2) * s_scale[2];
    }
  }
}

// ---------------- three_nn: 4 points per wave, |m|^2 precomputed ----------------
__global__ __launch_bounds__(256) void three_nn_kernel(
    const float* __restrict__ q_pos, const float* __restrict__ shp,
    float* __restrict__ w3, int* __restrict__ i3) {
  __shared__ float sx[NN], sy[NN], sz[NN];
  __shared__ double sq[NN];
  int b = blockIdx.y;
  int t = threadIdx.x;
  const float* qp = q_pos + (size_t)b * NN * 3;
  for (int i = t; i < NN; i += 256) {
    float x = qp[i * 3 + 0], y = qp[i * 3 + 1], z = qp[i * 3 + 2];
    sx[i] = x; sy[i] = y; sz[i] = z;
    sq[i] = (double)x * x + (double)y * y + (double)z * z;
  }
  __syncthreads();
  int wave = t >> 6, lane = t & 63;
  for (int pp = 0; pp < 4; ++pp) {
    int p = blockIdx.x * 16 + wave * 4 + pp;
    const float* spnt = shp + ((size_t)b * NKK + p) * 3;
    double px = (double)spnt[0], py = (double)spnt[1], pz = (double)spnt[2];
    double sp = px * px + py * py + pz * pz;
    double d0 = 1e300, d1 = 1e300, d2 = 1e300;
    int i0 = -1, i1 = -1, i2 = -1;
    #pragma unroll 4
    for (int j = 0; j < 16; ++j) {
      int m = lane + (j << 6);
      double dot = px * sx[m] + py * sy[m] + pz * sz[m];
      double d = sp + sq[m] - 2.0 * dot;
      if (d < 0.0) d = 0.0;
      if (d < d2) {
        if (d < d1) {
          d2 = d1; i2 = i1;
          if (d < d0) { d1 = d0; i1 = i0; d0 = d; i0 = m; }
          else { d1 = d; i1 = m; }
        } else { d2 = d; i2 = m; }
      }
    }
    double wd[3]; int wi[3];
    #pragma unroll
    for (int s = 0; s < 3; ++s) {
      double d = d0; int i = i0;
      #pragma unroll
      for (int off = 32; off > 0; off >>= 1) {
        double od = __shfl_xor(d, off, 64);
        int oi = __shfl_xor(i, off, 64);
        if (od < d || (od == d && oi < i)) { d = od; i = oi; }
      }
      if (i0 == i) { d0 = d1; i0 = i1; d1 = d2; i1 = i2; d2 = 1e300; i2 = -1; }
      wd[s] = d; wi[s] = i;
    }
    if (lane == 0) {
      double w0 = 1.0 / (wd[0] + 1e-8), w1 = 1.0 / (wd[1] + 1e-8), w2 = 1.0 / (wd[2] + 1e-8);
      double s = w0 + w1 + w2;
      float* wp = w3 + ((size_t)b * NKK + p) * 3;
      int* ip = i3 + ((size_t)b * NKK + p) * 3;
      wp[0] = (float)(w0 / s); wp[1] = (float)(w1 / s); wp[2] = (float)(w2 / s);
      ip[0] = wi[0]; ip[1] = wi[1]; ip[2] = wi[2];
    }
  }
}

// ------- final: 4 n per block, float4 cols ---------------------------------------
__global__ __launch_bounds__(384) void final_kernel(
    const float* __restrict__ Cat_pb,
    const float* __restrict__ w3, const int* __restrict__ i3,
    float* __restrict__ out) {
  int b = blockIdx.y;
  int t = threadIdx.x;
  __shared__ float sw[4][KK * 3];
  __shared__ int si[4][KK * 3];
  if (t < 4 * KK * 3) {
    int nl2 = t / (KK * 3), rr = t % (KK * 3);
    size_t base = ((size_t)b * NKK + ((size_t)blockIdx.x * 4 + nl2) * KK) * 3 + rr;
    sw[nl2][rr] = w3[base];
    si[nl2][rr] = i3[base];
  }
  __syncthreads();
  int nl = t / 96, c4 = (t % 96) * 4;
  int n = blockIdx.x * 4 + nl;
  size_t bn = (size_t)b * NN + n;
  const float* Pb = Cat_pb + (size_t)b * NN * (2 * CC);
  float4 base = *reinterpret_cast<const float4*>(Cat_pb + bn * (2 * CC) + CC + c4);
  float4 best = {-1e30f, -1e30f, -1e30f, -1e30f};
  #pragma unroll
  for (int k = 0; k < KK; ++k) {
    float4 acc = base;
    #pragma unroll
    for (int tt = 0; tt < 3; ++tt) {
      float wgt = sw[nl][k * 3 + tt];
      const float4 pv = *reinterpret_cast<const float4*>(Pb + (size_t)si[nl][k * 3 + tt] * (2 * CC) + c4);
      acc.x += wgt * pv.x; acc.y += wgt * pv.y; acc.z += wgt * pv.z; acc.w += wgt * pv.w;
    }
    acc.x = acc.x >= 0.f ? acc.x : 0.2f * acc.x;
    acc.y = acc.y >= 0.f ? acc.y : 0.2f * acc.y;
    acc.z = acc.z >= 0.f ? acc.z : 0.2f * acc.z;
    acc.w = acc.w >= 0.f ? acc.w : 0.2f * acc.w;
    best.x = fmaxf(best.x, acc.x); best.y = fmaxf(best.y, acc.y);
    best.z = fmaxf(best.z, acc.z); best.w = fmaxf(best.w, acc.w);
  }
  *reinterpret_cast<float4*>(out + bn * CC + c4) = best;
}

extern "C" void kernel_launch(void* const* d_in, const int* in_sizes, int n_in,
                              void* d_out, int out_size, void* d_ws, size_t ws_size,
                              hipStream_t stream) {
  (void)in_sizes; (void)n_in; (void)out_size; (void)ws_size;
  const float* q    = (const float*)d_in[0];
  const float* qpos = (const float*)d_in[1];
  const float* Wv   = (const float*)d_in[2];
  const float* bv   = (const float*)d_in[3];
  const float* W1   = (const float*)d_in[4];
  const float* b1   = (const float*)d_in[5];
  const float* lng  = (const float*)d_in[6];
  const float* lnb  = (const float*)d_in[7];
  const float* W2   = (const float*)d_in[8];
  const float* Wk   = (const float*)d_in[9];
  const float* bk   = (const float*)d_in[10];
  float* out = (float*)d_out;

  float* ws = (float*)d_ws;
  float* Cat_uv = ws; ws += (size_t)BB * NN * 2 * CC;   // [4096][768] U|V
  float* Cat_pb = ws; ws += (size_t)BB * NN * 2 * CC;   // [4096][768] P|Bse
  float* M1p = Cat_pb;                                   // alias: dead before Cat_pb written
  float* Bcat_uv = ws; ws += (size_t)CC * 2 * CC;
  float* bias_uv = ws; ws += 2 * CC;
  float* bias_pb = ws; ws += 2 * CC;
  float* shp = ws; ws += (size_t)BB * NKK * 3;
  float* w3  = ws; ws += (size_t)BB * NKK * 3;
  unsigned short* qb = (unsigned short*)ws;             // [4096][384] bf16
  ws += (size_t)BB * NN * CC / 2;
  unsigned short* Wt = (unsigned short*)ws;             // [768][384] bf16
  ws += (size_t)2 * CC * CC / 2;
  int* idxk = (int*)ws;
  int* i3   = idxk + (size_t)BB * NN * KK;

  // prep
  cvt_bf16_kernel<<<dim3(BB * NN * CC / 1024), dim3(256), 0, stream>>>(q, qb);
  biasprep_kernel<<<dim3(3), dim3(256), 0, stream>>>(W1, b1, bv, bk, bias_uv, bias_pb);
  pack_pb_kernel<<<dim3(2 * CC * CC / 256), dim3(256), 0, stream>>>(Wk, Wt);
  // M1 partials (split-K=8) into M1p, then pack into Bcat_uv
  gemm128_kernel<<<dim3(CC / 128, CC / 128, 8), dim3(256), 0, stream>>>(
      Wv, W1, M1p, nullptr, CC, CC, CC, 8);
  pack_uv_kernel<<<dim3(CC * 2 * CC / 256), dim3(256), 0, stream>>>(M1p, W1, Bcat_uv);
  // Cat_uv = q @ Bcat_uv + [0|c1]   (f32: topology-sensitive)
  gemm128_kernel<<<dim3(2 * CC / 128, BB * NN / 128, 1), dim3(256), 0, stream>>>(
      q, Bcat_uv, Cat_uv, bias_uv, BB * NN, 2 * CC, CC, 1);
  // Cat_pb = qb @ Wt^T + [0|bk]     (bf16 MFMA: linear in output)
  gemm_pb_kernel<<<dim3(2 * CC / 128, BB * NN / 128), dim3(256), 0, stream>>>(
      qb, Wt, Cat_pb, bias_pb);

  knn_kernel<<<dim3(NN / 4, BB), dim3(256), 0, stream>>>(qpos, idxk);
  mlp_kernel<<<dim3(BB * NN), dim3(64), 0, stream>>>(Cat_uv, lng, lnb, W2, idxk, qpos, shp);
  three_nn_kernel<<<dim3(NKK / 16, BB), dim3(256), 0, stream>>>(qpos, shp, w3, i3);
  final_kernel<<<dim3(NN / 4, BB), dim3(384), 0, stream>>>(Cat_pb, w3, i3, out);
}

// Round 4
// 174.664 us; speedup vs baseline: 1.3947x; 1.3947x over previous
//
#include <hip/hip_runtime.h>
#include <math.h>

#define BB 4
#define NN 1024
#define CC 384
#define KK 10
#define NKK (NN*KK)

typedef __attribute__((ext_vector_type(8))) short short8v;
typedef __attribute__((ext_vector_type(8))) unsigned short ushort8v;
typedef __attribute__((ext_vector_type(4))) float f32x4;

__device__ __forceinline__ float wave_sum(float v) {
  #pragma unroll
  for (int off = 32; off > 0; off >>= 1) v += __shfl_xor(v, off, 64);
  return v;
}

__device__ __forceinline__ unsigned short f2bf(float x) {
  unsigned int b = __float_as_uint(x);
  return (unsigned short)((b + 0x7fffu + ((b >> 16) & 1u)) >> 16);  // RNE
}
__device__ __forceinline__ float bf2f(unsigned short h) {
  return __uint_as_float(((unsigned int)h) << 16);
}

// ---------------- q -> (hi, lo) bf16 split ----------------
__global__ void cvt_split_kernel(const float* __restrict__ in,
                                 unsigned short* __restrict__ qh,
                                 unsigned short* __restrict__ ql) {
  int i = (blockIdx.x * 256 + threadIdx.x) * 4;
  float4 v = *reinterpret_cast<const float4*>(in + i);
  float x[4] = {v.x, v.y, v.z, v.w};
  #pragma unroll
  for (int j = 0; j < 4; ++j) {
    unsigned short h = f2bf(x[j]);
    qh[i + j] = h;
    ql[i + j] = f2bf(x[j] - bf2f(h));
  }
}

// ---------------- bias_uv = [0 | c1], bias_pb = [0 | bk] ----------------
__global__ void biasprep_kernel(const float* __restrict__ W1, const float* __restrict__ b1,
                                const float* __restrict__ bv, const float* __restrict__ bk,
                                float* __restrict__ bias_uv, float* __restrict__ bias_pb) {
  int j = blockIdx.x * 256 + threadIdx.x;
  if (j >= 2 * CC) return;
  if (j < CC) { bias_uv[j] = 0.f; bias_pb[j] = 0.f; }
  else {
    int c = j - CC;
    float s = b1[c];
    for (int i = 0; i < CC; ++i) s += bv[i] * W1[i * CC + c];
    bias_uv[j] = s;          // c1
    bias_pb[j] = bk[c];
  }
}

// ---------------- Wt_pb[n][k] (bf16): n<384 -> Wk_top[k][n]; else Wkdiff ----------------
__global__ void pack_pb_kernel(const float* __restrict__ Wk, unsigned short* __restrict__ Wt) {
  int idx = blockIdx.x * 256 + threadIdx.x;   // 768*384
  int n = idx / CC, k = idx % CC;
  float v;
  if (n < CC) v = Wk[(size_t)k * CC + n];
  else        v = Wk[(size_t)CC * CC + k * CC + (n - CC)] - Wk[(size_t)k * CC + (n - CC)];
  Wt[(size_t)n * CC + k] = f2bf(v);
}

// ------- Buv_t[n][k] = (n<384 ? M1[k][n] : W1_bot[k][n-384]) split hi/lo -------------
__global__ void pack_uv_split_kernel(const float* __restrict__ M1p, const float* __restrict__ W1,
                                     unsigned short* __restrict__ Buvh,
                                     unsigned short* __restrict__ Buvl) {
  int idx = blockIdx.x * 256 + threadIdx.x;   // 384*768, k-major for coalesced reads
  int k = idx / (2 * CC), n = idx % (2 * CC);
  float val;
  if (n < CC) {
    float s = 0.f;
    #pragma unroll
    for (int p = 0; p < 8; ++p) s += M1p[(size_t)p * CC * CC + (size_t)k * CC + n];
    val = s;
  } else {
    val = W1[(size_t)(CC + k) * CC + (n - CC)];
  }
  unsigned short h = f2bf(val);
  Buvh[(size_t)n * CC + k] = h;
  Buvl[(size_t)n * CC + k] = f2bf(val - bf2f(h));
}

// ---------------- f32 GEMM 128x128 tile, 8x8/thread, split-K (used for M1 only) ------
__global__ __launch_bounds__(256) void gemm128_kernel(
    const float* __restrict__ A, const float* __restrict__ Bm,
    float* __restrict__ Cm, const float* __restrict__ bias,
    int M, int Ncol, int Kd, int ksplit) {
  __shared__ float As[16][132];
  __shared__ float Bs[16][128];
  int tid = threadIdx.x;
  int tx = tid & 15, ty = tid >> 4;
  int row0 = blockIdx.y * 128, col0 = blockIdx.x * 128;
  int klen = Kd / ksplit;
  int k0 = blockIdx.z * klen;
  float acc[8][8] = {};
  int arow = tid >> 2, akc = (tid & 3) << 2;
  int brow = tid >> 5, bcol = (tid & 31) << 2;
  for (int kt = k0; kt < k0 + klen; kt += 16) {
    #pragma unroll
    for (int h = 0; h < 2; ++h) {
      int r = arow + 64 * h;
      float4 av = *reinterpret_cast<const float4*>(A + (size_t)(row0 + r) * Kd + kt + akc);
      As[akc + 0][r] = av.x; As[akc + 1][r] = av.y;
      As[akc + 2][r] = av.z; As[akc + 3][r] = av.w;
    }
    #pragma unroll
    for (int h = 0; h < 2; ++h) {
      int r = brow + 8 * h;
      float4 bv4 = *reinterpret_cast<const float4*>(Bm + (size_t)(kt + r) * Ncol + col0 + bcol);
      *reinterpret_cast<float4*>(&Bs[r][bcol]) = bv4;
    }
    __syncthreads();
    #pragma unroll
    for (int kk = 0; kk < 16; ++kk) {
      float4 a0 = *reinterpret_cast<const float4*>(&As[kk][ty << 2]);
      float4 a1 = *reinterpret_cast<const float4*>(&As[kk][64 + (ty << 2)]);
      float4 b0 = *reinterpret_cast<const float4*>(&Bs[kk][tx << 2]);
      float4 b1 = *reinterpret_cast<const float4*>(&Bs[kk][64 + (tx << 2)]);
      float av_[8] = {a0.x, a0.y, a0.z, a0.w, a1.x, a1.y, a1.z, a1.w};
      float bv_[8] = {b0.x, b0.y, b0.z, b0.w, b1.x, b1.y, b1.z, b1.w};
      #pragma unroll
      for (int i = 0; i < 8; ++i) {
        #pragma unroll
        for (int j = 0; j < 8; ++j) acc[i][j] += av_[i] * bv_[j];
      }
    }
    __syncthreads();
  }
  float* Cz = Cm + (size_t)blockIdx.z * M * Ncol;
  #pragma unroll
  for (int i = 0; i < 8; ++i) {
    int row = row0 + (ty << 2) + (i & 3) + ((i & 4) << 4);
    #pragma unroll
    for (int h = 0; h < 2; ++h) {
      int col = col0 + 64 * h + (tx << 2);
      float4 r;
      r.x = acc[i][4 * h + 0]; r.y = acc[i][4 * h + 1];
      r.z = acc[i][4 * h + 2]; r.w = acc[i][4 * h + 3];
      if (bias) { r.x += bias[col]; r.y += bias[col + 1]; r.z += bias[col + 2]; r.w += bias[col + 3]; }
      *reinterpret_cast<float4*>(Cz + (size_t)row * Ncol + col) = r;
    }
  }
}

// ------- merged MFMA GEMM: z=0: Cuv = q@Buv (bf16x2-split, 3 products)
//                           z=1: Cpb = q@Wt^T (bf16, 1 product) ------------------------
__global__ __launch_bounds__(256) void gemm_mfma_kernel(
    const unsigned short* __restrict__ qh, const unsigned short* __restrict__ ql,
    const unsigned short* __restrict__ Buvh, const unsigned short* __restrict__ Buvl,
    const unsigned short* __restrict__ Wt,
    float* __restrict__ Cuv, float* __restrict__ Cpb,
    const float* __restrict__ bias_uv, const float* __restrict__ bias_pb) {
  int path = blockIdx.z;                 // 0 = uv (split), 1 = pb
  const unsigned short* Bh = path ? Wt : Buvh;
  float* Cm = path ? Cpb : Cuv;
  const float* bias = path ? bias_pb : bias_uv;
  __shared__ unsigned short Ah[128 * 32], Alo[128 * 32];
  __shared__ unsigned short Bhs[128 * 32], Bls[128 * 32];
  int tid = threadIdx.x;
  int lane = tid & 63, w = tid >> 6;
  int m0 = blockIdx.y * 128, n0 = blockIdx.x * 128;
  f32x4 acc[4][4];
  #pragma unroll
  for (int i = 0; i < 4; ++i)
    #pragma unroll
    for (int j = 0; j < 4; ++j) acc[i][j] = (f32x4){0.f, 0.f, 0.f, 0.f};
  int rl = lane & 15, kg = lane >> 4;
  for (int k0 = 0; k0 < CC; k0 += 32) {
    #pragma unroll
    for (int j = 0; j < 2; ++j) {
      int id = tid + 256 * j;
      int r = id >> 2, s = id & 3;
      int sw = (s ^ (r & 3)) * 8;
      *reinterpret_cast<ushort8v*>(Ah + r * 32 + sw) =
          *reinterpret_cast<const ushort8v*>(qh + (size_t)(m0 + r) * CC + k0 + s * 8);
      *reinterpret_cast<ushort8v*>(Bhs + r * 32 + sw) =
          *reinterpret_cast<const ushort8v*>(Bh + (size_t)(n0 + r) * CC + k0 + s * 8);
      if (!path) {
        *reinterpret_cast<ushort8v*>(Alo + r * 32 + sw) =
            *reinterpret_cast<const ushort8v*>(ql + (size_t)(m0 + r) * CC + k0 + s * 8);
        *reinterpret_cast<ushort8v*>(Bls + r * 32 + sw) =
            *reinterpret_cast<const ushort8v*>(Buvl + (size_t)(n0 + r) * CC + k0 + s * 8);
      }
    }
    __syncthreads();
    short8v afh[4], bfh[4], afl[4], bfl[4];
    #pragma unroll
    for (int f = 0; f < 4; ++f) {
      int ar = (w & 1) * 64 + f * 16 + rl;
      int aof = ar * 32 + (kg ^ (ar & 3)) * 8;
      int br = (w >> 1) * 64 + f * 16 + rl;
      int bof = br * 32 + (kg ^ (br & 3)) * 8;
      afh[f] = *reinterpret_cast<const short8v*>(Ah + aof);
      bfh[f] = *reinterpret_cast<const short8v*>(Bhs + bof);
      if (!path) {
        afl[f] = *reinterpret_cast<const short8v*>(Alo + aof);
        bfl[f] = *reinterpret_cast<const short8v*>(Bls + bof);
      }
    }
    #pragma unroll
    for (int i = 0; i < 4; ++i) {
      #pragma unroll
      for (int j = 0; j < 4; ++j) {
        acc[i][j] = __builtin_amdgcn_mfma_f32_16x16x32_bf16(afh[i], bfh[j], acc[i][j], 0, 0, 0);
        if (!path) {
          acc[i][j] = __builtin_amdgcn_mfma_f32_16x16x32_bf16(afh[i], bfl[j], acc[i][j], 0, 0, 0);
          acc[i][j] = __builtin_amdgcn_mfma_f32_16x16x32_bf16(afl[i], bfh[j], acc[i][j], 0, 0, 0);
        }
      }
    }
    __syncthreads();
  }
  // C/D layout: col = lane&15, row = (lane>>4)*4 + reg
  #pragma unroll
  for (int i = 0; i < 4; ++i) {
    #pragma unroll
    for (int j = 0; j < 4; ++j) {
      int col = n0 + (w >> 1) * 64 + j * 16 + rl;
      float bcol_v = bias[col];
      #pragma unroll
      for (int r = 0; r < 4; ++r) {
        int row = m0 + (w & 1) * 64 + i * 16 + kg * 4 + r;
        Cm[(size_t)row * (2 * CC) + col] = acc[i][j][r] + bcol_v;
      }
    }
  }
}

// ---------------- KNN (f32): one wave per query; float4 (x,y,z,|m|^2) in LDS ---------
__global__ __launch_bounds__(256) void knn_kernel(const float* __restrict__ q_pos,
                                                  int* __restrict__ idx_out) {
  __shared__ float4 sp4[NN];
  int b = blockIdx.y;
  int t = threadIdx.x;
  const float* qp = q_pos + (size_t)b * NN * 3;
  for (int i = t; i < NN; i += 256) {
    float x = qp[i * 3 + 0], y = qp[i * 3 + 1], z = qp[i * 3 + 2];
    sp4[i] = (float4){x, y, z, x * x + y * y + z * z};
  }
  __syncthreads();
  int wave = t >> 6, lane = t & 63;
  int n = blockIdx.x * 4 + wave;
  float4 me = sp4[n];
  float px = me.x, py = me.y, pz = me.z, sp = me.w;
  float bd[KK]; int bi[KK];
  #pragma unroll
  for (int s = 0; s < KK; ++s) { bd[s] = 1e30f; bi[s] = -1; }
  #pragma unroll 4
  for (int j = 0; j < 16; ++j) {
    int m = lane + (j << 6);
    float4 c = sp4[m];
    float dot = fmaf(px, c.x, fmaf(py, c.y, pz * c.z));
    float d = fmaf(-2.f, dot, sp + c.w);
    d = fmaxf(d, 0.f);
    if (d < bd[KK - 1]) {
      bd[KK - 1] = d; bi[KK - 1] = m;
      #pragma unroll
      for (int s = KK - 1; s >= 1; --s) {
        if (bd[s] < bd[s - 1]) {
          float td = bd[s]; bd[s] = bd[s - 1]; bd[s - 1] = td;
          int ti = bi[s]; bi[s] = bi[s - 1]; bi[s - 1] = ti;
        }
      }
    }
  }
  int* op = idx_out + ((size_t)b * NN + n) * KK;
  for (int s = 0; s < KK; ++s) {
    float d = bd[0]; int i = bi[0];
    #pragma unroll
    for (int off = 32; off > 0; off >>= 1) {
      float od = __shfl_xor(d, off, 64);
      int oi = __shfl_xor(i, off, 64);
      if (od < d || (od == d && oi < i)) { d = od; i = oi; }
    }
    if (bi[0] == i) {
      #pragma unroll
      for (int u = 0; u < KK - 1; ++u) { bd[u] = bd[u + 1]; bi[u] = bi[u + 1]; }
      bd[KK - 1] = 1e30f; bi[KK - 1] = -1;
    }
    if (lane == 0) op[s] = i;
  }
}

// -------- fused MLP per (b,n): loop k; h=U[idx]+V -> LN -> gelu -> tanh(h@W2) --------
__global__ __launch_bounds__(64) void mlp_kernel(
    const float* __restrict__ Cat_uv, const float* __restrict__ lng, const float* __restrict__ lnb,
    const float* __restrict__ W2, const int* __restrict__ idxk, const float* __restrict__ q_pos,
    float* __restrict__ shp) {
  int bn = blockIdx.x;
  int b = bn >> 10;
  int lane = threadIdx.x;
  __shared__ int s_nb[KK];
  __shared__ float s_scale[3], s_lvp[KK][3];
  if (lane < KK) s_nb[lane] = idxk[(size_t)bn * KK + lane];
  __syncthreads();
  if (lane < 3) {
    float mx = -1e30f, mn = 1e30f;
    #pragma unroll
    for (int k2 = 0; k2 < KK; ++k2) {
      float v = q_pos[((size_t)b * NN + s_nb[k2]) * 3 + lane];
      mx = fmaxf(mx, v); mn = fminf(mn, v);
      s_lvp[k2][lane] = v;
    }
    s_scale[lane] = (mx - mn) * 0.5f;
  }
  __syncthreads();
  float Vv[6], lg[6], lb[6], w2a[6], w2b[6], w2c[6];
  const float* Vrow = Cat_uv + (size_t)bn * (2 * CC) + CC;
  #pragma unroll
  for (int i = 0; i < 6; ++i) {
    int c = lane + (i << 6);
    Vv[i] = Vrow[c];
    lg[i] = lng[c]; lb[i] = lnb[c];
    w2a[i] = W2[c * 3 + 0]; w2b[i] = W2[c * 3 + 1]; w2c[i] = W2[c * 3 + 2];
  }
  for (int k = 0; k < KK; ++k) {
    const float* Urow = Cat_uv + ((size_t)b * NN + s_nb[k]) * (2 * CC);
    float h[6];
    float ls = 0.f;
    #pragma unroll
    for (int i = 0; i < 6; ++i) {
      h[i] = Urow[lane + (i << 6)] + Vv[i];
      ls += h[i];
    }
    ls = wave_sum(ls);
    float mu = ls * (1.0f / CC);
    float lv = 0.f;
    #pragma unroll
    for (int i = 0; i < 6; ++i) { float d = h[i] - mu; lv += d * d; }
    lv = wave_sum(lv);
    float rstd = 1.0f / sqrtf(lv * (1.0f / CC) + 1e-5f);
    float o0 = 0.f, o1 = 0.f, o2 = 0.f;
    #pragma unroll
    for (int i = 0; i < 6; ++i) {
      float x = (h[i] - mu) * rstd * lg[i] + lb[i];
      float g = 0.5f * x * (1.0f + erff(x * 0.70710678118654752440f));
      o0 += g * w2a[i]; o1 += g * w2b[i]; o2 += g * w2c[i];
    }
    o0 = wave_sum(o0); o1 = wave_sum(o1); o2 = wave_sum(o2);
    if (lane == 0) {
      float* sp = shp + ((size_t)bn * KK + k) * 3;
      sp[0] = s_lvp[k][0] + tanhf(o0) * s_scale[0];
      sp[1] = s_lvp[k][1] + tanhf(o1) * s_scale[1];
      sp[2] = s_lvp[k][2] + tanhf(o2) * s_scale[2];
    }
  }
}

// ------- three_nn (f32): 4 pts/wave, float4 LDS, branchless top-3 --------------------
__global__ __launch_bounds__(256) void three_nn_kernel(
    const float* __restrict__ q_pos, const float* __restrict__ shp,
    float* __restrict__ w3, int* __restrict__ i3) {
  __shared__ float4 sp4[NN];
  int b = blockIdx.y;
  int t = threadIdx.x;
  const float* qp = q_pos + (size_t)b * NN * 3;
  for (int i = t; i < NN; i += 256) {
    float x = qp[i * 3 + 0], y = qp[i * 3 + 1], z = qp[i * 3 + 2];
    sp4[i] = (float4){x, y, z, x * x + y * y + z * z};
  }
  __syncthreads();
  int wave = t >> 6, lane = t & 63;
  for (int pp = 0; pp < 4; ++pp) {
    int p = blockIdx.x * 16 + wave * 4 + pp;
    const float* spnt = shp + ((size_t)b * NKK + p) * 3;
    float px = spnt[0], py = spnt[1], pz = spnt[2];
    float sp = fmaf(px, px, fmaf(py, py, pz * pz));
    float d0 = 1e30f, d1 = 1e30f, d2 = 1e30f;
    int i0 = -1, i1 = -1, i2 = -1;
    #pragma unroll 4
    for (int j = 0; j < 16; ++j) {
      int m = lane + (j << 6);
      float4 c = sp4[m];
      float dot = fmaf(px, c.x, fmaf(py, c.y, pz * c.z));
      float d = fmaf(-2.f, dot, sp + c.w);
      d = fmaxf(d, 0.f);
      bool c2 = d < d2, c1 = d < d1, c0 = d < d0;
      d2 = c1 ? d1 : (c2 ? d : d2);  i2 = c1 ? i1 : (c2 ? m : i2);
      d1 = c0 ? d0 : (c1 ? d : d1);  i1 = c0 ? i0 : (c1 ? m : i1);
      d0 = c0 ? d : d0;              i0 = c0 ? m : i0;
    }
    float wd[3]; int wi[3];
    #pragma unroll
    for (int s = 0; s < 3; ++s) {
      float d = d0; int i = i0;
      #pragma unroll
      for (int off = 32; off > 0; off >>= 1) {
        float od = __shfl_xor(d, off, 64);
        int oi = __shfl_xor(i, off, 64);
        if (od < d || (od == d && oi < i)) { d = od; i = oi; }
      }
      if (i0 == i) { d0 = d1; i0 = i1; d1 = d2; i1 = i2; d2 = 1e30f; i2 = -1; }
      wd[s] = d; wi[s] = i;
    }
    if (lane == 0) {
      float w0 = 1.f / (wd[0] + 1e-8f), w1 = 1.f / (wd[1] + 1e-8f), w2 = 1.f / (wd[2] + 1e-8f);
      float s = w0 + w1 + w2;
      float* wp = w3 + ((size_t)b * NKK + p) * 3;
      int* ip = i3 + ((size_t)b * NKK + p) * 3;
      wp[0] = w0 / s; wp[1] = w1 / s; wp[2] = w2 / s;
      ip[0] = wi[0]; ip[1] = wi[1]; ip[2] = wi[2];
    }
  }
}

// ------- final: 4 n per block, float4 cols ---------------------------------------
__global__ __launch_bounds__(384) void final_kernel(
    const float* __restrict__ Cat_pb,
    const float* __restrict__ w3, const int* __restrict__ i3,
    float* __restrict__ out) {
  int b = blockIdx.y;
  int t = threadIdx.x;
  __shared__ float sw[4][KK * 3];
  __shared__ int si[4][KK * 3];
  if (t < 4 * KK * 3) {
    int nl2 = t / (KK * 3), rr = t % (KK * 3);
    size_t base = ((size_t)b * NKK + ((size_t)blockIdx.x * 4 + nl2) * KK) * 3 + rr;
    sw[nl2][rr] = w3[base];
    si[nl2][rr] = i3[base];
  }
  __syncthreads();
  int nl = t / 96, c4 = (t % 96) * 4;
  int n = blockIdx.x * 4 + nl;
  size_t bn = (size_t)b * NN + n;
  const float* Pb = Cat_pb + (size_t)b * NN * (2 * CC);
  float4 base = *reinterpret_cast<const float4*>(Cat_pb + bn * (2 * CC) + CC + c4);
  float4 best = {-1e30f, -1e30f, -1e30f, -1e30f};
  #pragma unroll
  for (int k = 0; k < KK; ++k) {
    float4 acc = base;
    #pragma unroll
    for (int tt = 0; tt < 3; ++tt) {
      float wgt = sw[nl][k * 3 + tt];
      const float4 pv = *reinterpret_cast<const float4*>(Pb + (size_t)si[nl][k * 3 + tt] * (2 * CC) + c4);
      acc.x += wgt * pv.x; acc.y += wgt * pv.y; acc.z += wgt * pv.z; acc.w += wgt * pv.w;
    }
    acc.x = acc.x >= 0.f ? acc.x : 0.2f * acc.x;
    acc.y = acc.y >= 0.f ? acc.y : 0.2f * acc.y;
    acc.z = acc.z >= 0.f ? acc.z : 0.2f * acc.z;
    acc.w = acc.w >= 0.f ? acc.w : 0.2f * acc.w;
    best.x = fmaxf(best.x, acc.x); best.y = fmaxf(best.y, acc.y);
    best.z = fmaxf(best.z, acc.z); best.w = fmaxf(best.w, acc.w);
  }
  *reinterpret_cast<float4*>(out + bn * CC + c4) = best;
}

extern "C" void kernel_launch(void* const* d_in, const int* in_sizes, int n_in,
                              void* d_out, int out_size, void* d_ws, size_t ws_size,
                              hipStream_t stream) {
  (void)in_sizes; (void)n_in; (void)out_size; (void)ws_size;
  const float* q    = (const float*)d_in[0];
  const float* qpos = (const float*)d_in[1];
  const float* Wv   = (const float*)d_in[2];
  const float* bv   = (const float*)d_in[3];
  const float* W1   = (const float*)d_in[4];
  const float* b1   = (const float*)d_in[5];
  const float* lng  = (const float*)d_in[6];
  const float* lnb  = (const float*)d_in[7];
  const float* W2   = (const float*)d_in[8];
  const float* Wk   = (const float*)d_in[9];
  const float* bk   = (const float*)d_in[10];
  float* out = (float*)d_out;

  float* ws = (float*)d_ws;
  float* Cat_uv = ws; ws += (size_t)BB * NN * 2 * CC;   // [4096][768] U|V
  float* Cat_pb = ws; ws += (size_t)BB * NN * 2 * CC;   // [4096][768] P|Bse
  float* M1p = Cat_pb;                                   // alias: consumed before Cat_pb written
  float* bias_uv = ws; ws += 2 * CC;
  float* bias_pb = ws; ws += 2 * CC;
  float* shp = ws; ws += (size_t)BB * NKK * 3;
  float* w3  = ws; ws += (size_t)BB * NKK * 3;
  unsigned short* qh = (unsigned short*)ws;  ws += (size_t)BB * NN * CC / 2;
  unsigned short* ql = (unsigned short*)ws;  ws += (size_t)BB * NN * CC / 2;
  unsigned short* Wt = (unsigned short*)ws;  ws += (size_t)2 * CC * CC / 2;
  unsigned short* Buvh = (unsigned short*)ws; ws += (size_t)2 * CC * CC / 2;
  unsigned short* Buvl = (unsigned short*)ws; ws += (size_t)2 * CC * CC / 2;
  int* idxk = (int*)ws;
  int* i3   = idxk + (size_t)BB * NN * KK;

  // prep
  cvt_split_kernel<<<dim3(BB * NN * CC / 1024), dim3(256), 0, stream>>>(q, qh, ql);
  biasprep_kernel<<<dim3(3), dim3(256), 0, stream>>>(W1, b1, bv, bk, bias_uv, bias_pb);
  pack_pb_kernel<<<dim3(2 * CC * CC / 256), dim3(256), 0, stream>>>(Wk, Wt);
  // M1 partials (split-K=8), then pack+split into Buvh/Buvl
  gemm128_kernel<<<dim3(CC / 128, CC / 128, 8), dim3(256), 0, stream>>>(
      Wv, W1, M1p, nullptr, CC, CC, CC, 8);
  pack_uv_split_kernel<<<dim3(CC * 2 * CC / 256), dim3(256), 0, stream>>>(M1p, W1, Buvh, Buvl);
  // one dispatch: z=0 -> Cat_uv (bf16x2-split, ~f32 accuracy); z=1 -> Cat_pb (bf16)
  gemm_mfma_kernel<<<dim3(2 * CC / 128, BB * NN / 128, 2), dim3(256), 0, stream>>>(
      qh, ql, Buvh, Buvl, Wt, Cat_uv, Cat_pb, bias_uv, bias_pb);

  knn_kernel<<<dim3(NN / 4, BB), dim3(256), 0, stream>>>(qpos, idxk);
  mlp_kernel<<<dim3(BB * NN), dim3(64), 0, stream>>>(Cat_uv, lng, lnb, W2, idxk, qpos, shp);
  three_nn_kernel<<<dim3(NKK / 16, BB), dim3(256), 0, stream>>>(qpos, shp, w3, i3);
  final_kernel<<<dim3(NN / 4, BB), dim3(384), 0, stream>>>(Cat_pb, w3, i3, out);
}

// Round 5
// 167.318 us; speedup vs baseline: 1.4560x; 1.0439x over previous
//
#include <hip/hip_runtime.h>
#include <math.h>

#define BB 4
#define NN 1024
#define CC 384
#define KK 10
#define NKK (NN*KK)

typedef __attribute__((ext_vector_type(8))) short short8v;
typedef __attribute__((ext_vector_type(8))) unsigned short ushort8v;
typedef __attribute__((ext_vector_type(4))) float f32x4;

template <int NA>
__device__ __forceinline__ void wave_sum_arr(float* a) {
  #pragma unroll
  for (int off = 32; off > 0; off >>= 1) {
    float t[NA];
    #pragma unroll
    for (int u = 0; u < NA; ++u) t[u] = __shfl_xor(a[u], off, 64);
    #pragma unroll
    for (int u = 0; u < NA; ++u) a[u] += t[u];
  }
}

__device__ __forceinline__ unsigned short f2bf(float x) {
  unsigned int b = __float_as_uint(x);
  return (unsigned short)((b + 0x7fffu + ((b >> 16) & 1u)) >> 16);  // RNE
}
__device__ __forceinline__ float bf2f(unsigned short h) {
  return __uint_as_float(((unsigned int)h) << 16);
}

// ---------- fused prep: [0,1536) cvt_split | [1536,2688) pack_pb | [2688,2691) bias ----
#define NB_CVT  (BB * NN * CC / 1024)        // 1536
#define NB_PB   (2 * CC * CC / 256)          // 1152
__global__ void prep_kernel(const float* __restrict__ q,
                            const float* __restrict__ W1, const float* __restrict__ b1,
                            const float* __restrict__ bv, const float* __restrict__ bk,
                            const float* __restrict__ Wk,
                            unsigned short* __restrict__ qh, unsigned short* __restrict__ ql,
                            unsigned short* __restrict__ Wt,
                            float* __restrict__ bias_uv, float* __restrict__ bias_pb) {
  int blk = blockIdx.x;
  int tid = threadIdx.x;
  if (blk < NB_CVT) {
    int i = (blk * 256 + tid) * 4;
    float4 v = *reinterpret_cast<const float4*>(q + i);
    float x[4] = {v.x, v.y, v.z, v.w};
    #pragma unroll
    for (int j = 0; j < 4; ++j) {
      unsigned short h = f2bf(x[j]);
      qh[i + j] = h;
      ql[i + j] = f2bf(x[j] - bf2f(h));
    }
  } else if (blk < NB_CVT + NB_PB) {
    int idx = (blk - NB_CVT) * 256 + tid;    // 768*384
    int n = idx / CC, k = idx % CC;
    float v;
    if (n < CC) v = Wk[(size_t)k * CC + n];
    else        v = Wk[(size_t)CC * CC + k * CC + (n - CC)] - Wk[(size_t)k * CC + (n - CC)];
    Wt[(size_t)n * CC + k] = f2bf(v);
  } else {
    int j = (blk - NB_CVT - NB_PB) * 256 + tid;
    if (j >= 2 * CC) return;
    if (j < CC) { bias_uv[j] = 0.f; bias_pb[j] = 0.f; }
    else {
      int c = j - CC;
      float s = b1[c];
      for (int i = 0; i < CC; ++i) s += bv[i] * W1[i * CC + c];
      bias_uv[j] = s;          // c1
      bias_pb[j] = bk[c];
    }
  }
}

// ------- Buv_t[n][k] = (n<384 ? M1[k][n] : W1_bot[k][n-384]) split hi/lo -------------
__global__ void pack_uv_split_kernel(const float* __restrict__ M1p, const float* __restrict__ W1,
                                     unsigned short* __restrict__ Buvh,
                                     unsigned short* __restrict__ Buvl) {
  int idx = blockIdx.x * 256 + threadIdx.x;   // 384*768, k-major for coalesced reads
  int k = idx / (2 * CC), n = idx % (2 * CC);
  float val;
  if (n < CC) {
    float s = 0.f;
    #pragma unroll
    for (int p = 0; p < 8; ++p) s += M1p[(size_t)p * CC * CC + (size_t)k * CC + n];
    val = s;
  } else {
    val = W1[(size_t)(CC + k) * CC + (n - CC)];
  }
  unsigned short h = f2bf(val);
  Buvh[(size_t)n * CC + k] = h;
  Buvl[(size_t)n * CC + k] = f2bf(val - bf2f(h));
}

// ---------------- f32 GEMM 128x128 tile, 8x8/thread, split-K (used for M1 only) ------
__global__ __launch_bounds__(256) void gemm128_kernel(
    const float* __restrict__ A, const float* __restrict__ Bm,
    float* __restrict__ Cm, const float* __restrict__ bias,
    int M, int Ncol, int Kd, int ksplit) {
  __shared__ float As[16][132];
  __shared__ float Bs[16][128];
  int tid = threadIdx.x;
  int tx = tid & 15, ty = tid >> 4;
  int row0 = blockIdx.y * 128, col0 = blockIdx.x * 128;
  int klen = Kd / ksplit;
  int k0 = blockIdx.z * klen;
  float acc[8][8] = {};
  int arow = tid >> 2, akc = (tid & 3) << 2;
  int brow = tid >> 5, bcol = (tid & 31) << 2;
  for (int kt = k0; kt < k0 + klen; kt += 16) {
    #pragma unroll
    for (int h = 0; h < 2; ++h) {
      int r = arow + 64 * h;
      float4 av = *reinterpret_cast<const float4*>(A + (size_t)(row0 + r) * Kd + kt + akc);
      As[akc + 0][r] = av.x; As[akc + 1][r] = av.y;
      As[akc + 2][r] = av.z; As[akc + 3][r] = av.w;
    }
    #pragma unroll
    for (int h = 0; h < 2; ++h) {
      int r = brow + 8 * h;
      float4 bv4 = *reinterpret_cast<const float4*>(Bm + (size_t)(kt + r) * Ncol + col0 + bcol);
      *reinterpret_cast<float4*>(&Bs[r][bcol]) = bv4;
    }
    __syncthreads();
    #pragma unroll
    for (int kk = 0; kk < 16; ++kk) {
      float4 a0 = *reinterpret_cast<const float4*>(&As[kk][ty << 2]);
      float4 a1 = *reinterpret_cast<const float4*>(&As[kk][64 + (ty << 2)]);
      float4 b0 = *reinterpret_cast<const float4*>(&Bs[kk][tx << 2]);
      float4 b1 = *reinterpret_cast<const float4*>(&Bs[kk][64 + (tx << 2)]);
      float av_[8] = {a0.x, a0.y, a0.z, a0.w, a1.x, a1.y, a1.z, a1.w};
      float bv_[8] = {b0.x, b0.y, b0.z, b0.w, b1.x, b1.y, b1.z, b1.w};
      #pragma unroll
      for (int i = 0; i < 8; ++i) {
        #pragma unroll
        for (int j = 0; j < 8; ++j) acc[i][j] += av_[i] * bv_[j];
      }
    }
    __syncthreads();
  }
  float* Cz = Cm + (size_t)blockIdx.z * M * Ncol;
  #pragma unroll
  for (int i = 0; i < 8; ++i) {
    int row = row0 + (ty << 2) + (i & 3) + ((i & 4) << 4);
    #pragma unroll
    for (int h = 0; h < 2; ++h) {
      int col = col0 + 64 * h + (tx << 2);
      float4 r;
      r.x = acc[i][4 * h + 0]; r.y = acc[i][4 * h + 1];
      r.z = acc[i][4 * h + 2]; r.w = acc[i][4 * h + 3];
      if (bias) { r.x += bias[col]; r.y += bias[col + 1]; r.z += bias[col + 2]; r.w += bias[col + 3]; }
      *reinterpret_cast<float4*>(Cz + (size_t)row * Ncol + col) = r;
    }
  }
}

// ------- merged MFMA GEMM: z=0: Cuv = q@Buv (bf16x2-split, 3 products)
//                           z=1: Cpb = q@Wt^T (bf16, 1 product) ------------------------
__global__ __launch_bounds__(256) void gemm_mfma_kernel(
    const unsigned short* __restrict__ qh, const unsigned short* __restrict__ ql,
    const unsigned short* __restrict__ Buvh, const unsigned short* __restrict__ Buvl,
    const unsigned short* __restrict__ Wt,
    float* __restrict__ Cuv, float* __restrict__ Cpb,
    const float* __restrict__ bias_uv, const float* __restrict__ bias_pb) {
  int path = blockIdx.z;                 // 0 = uv (split), 1 = pb
  const unsigned short* Bh = path ? Wt : Buvh;
  float* Cm = path ? Cpb : Cuv;
  const float* bias = path ? bias_pb : bias_uv;
  __shared__ unsigned short Ah[128 * 32], Alo[128 * 32];
  __shared__ unsigned short Bhs[128 * 32], Bls[128 * 32];
  int tid = threadIdx.x;
  int lane = tid & 63, w = tid >> 6;
  int m0 = blockIdx.y * 128, n0 = blockIdx.x * 128;
  f32x4 acc[4][4];
  #pragma unroll
  for (int i = 0; i < 4; ++i)
    #pragma unroll
    for (int j = 0; j < 4; ++j) acc[i][j] = (f32x4){0.f, 0.f, 0.f, 0.f};
  int rl = lane & 15, kg = lane >> 4;
  for (int k0 = 0; k0 < CC; k0 += 32) {
    #pragma unroll
    for (int j = 0; j < 2; ++j) {
      int id = tid + 256 * j;
      int r = id >> 2, s = id & 3;
      int sw = (s ^ (r & 3)) * 8;
      *reinterpret_cast<ushort8v*>(Ah + r * 32 + sw) =
          *reinterpret_cast<const ushort8v*>(qh + (size_t)(m0 + r) * CC + k0 + s * 8);
      *reinterpret_cast<ushort8v*>(Bhs + r * 32 + sw) =
          *reinterpret_cast<const ushort8v*>(Bh + (size_t)(n0 + r) * CC + k0 + s * 8);
      if (!path) {
        *reinterpret_cast<ushort8v*>(Alo + r * 32 + sw) =
            *reinterpret_cast<const ushort8v*>(ql + (size_t)(m0 + r) * CC + k0 + s * 8);
        *reinterpret_cast<ushort8v*>(Bls + r * 32 + sw) =
            *reinterpret_cast<const ushort8v*>(Buvl + (size_t)(n0 + r) * CC + k0 + s * 8);
      }
    }
    __syncthreads();
    short8v afh[4], bfh[4], afl[4], bfl[4];
    #pragma unroll
    for (int f = 0; f < 4; ++f) {
      int ar = (w & 1) * 64 + f * 16 + rl;
      int aof = ar * 32 + (kg ^ (ar & 3)) * 8;
      int br = (w >> 1) * 64 + f * 16 + rl;
      int bof = br * 32 + (kg ^ (br & 3)) * 8;
      afh[f] = *reinterpret_cast<const short8v*>(Ah + aof);
      bfh[f] = *reinterpret_cast<const short8v*>(Bhs + bof);
      if (!path) {
        afl[f] = *reinterpret_cast<const short8v*>(Alo + aof);
        bfl[f] = *reinterpret_cast<const short8v*>(Bls + bof);
      }
    }
    #pragma unroll
    for (int i = 0; i < 4; ++i) {
      #pragma unroll
      for (int j = 0; j < 4; ++j) {
        acc[i][j] = __builtin_amdgcn_mfma_f32_16x16x32_bf16(afh[i], bfh[j], acc[i][j], 0, 0, 0);
        if (!path) {
          acc[i][j] = __builtin_amdgcn_mfma_f32_16x16x32_bf16(afh[i], bfl[j], acc[i][j], 0, 0, 0);
          acc[i][j] = __builtin_amdgcn_mfma_f32_16x16x32_bf16(afl[i], bfh[j], acc[i][j], 0, 0, 0);
        }
      }
    }
    __syncthreads();
  }
  // C/D layout: col = lane&15, row = (lane>>4)*4 + reg
  #pragma unroll
  for (int i = 0; i < 4; ++i) {
    #pragma unroll
    for (int j = 0; j < 4; ++j) {
      int col = n0 + (w >> 1) * 64 + j * 16 + rl;
      float bcol_v = bias[col];
      #pragma unroll
      for (int r = 0; r < 4; ++r) {
        int row = m0 + (w & 1) * 64 + i * 16 + kg * 4 + r;
        Cm[(size_t)row * (2 * CC) + col] = acc[i][j][r] + bcol_v;
      }
    }
  }
}

// ---------------- KNN (f32): one wave per query; float4 (x,y,z,|m|^2) in LDS ---------
__global__ __launch_bounds__(256) void knn_kernel(const float* __restrict__ q_pos,
                                                  int* __restrict__ idx_out) {
  __shared__ float4 sp4[NN];
  int b = blockIdx.y;
  int t = threadIdx.x;
  const float* qp = q_pos + (size_t)b * NN * 3;
  for (int i = t; i < NN; i += 256) {
    float x = qp[i * 3 + 0], y = qp[i * 3 + 1], z = qp[i * 3 + 2];
    sp4[i] = (float4){x, y, z, x * x + y * y + z * z};
  }
  __syncthreads();
  int wave = t >> 6, lane = t & 63;
  int n = blockIdx.x * 4 + wave;
  float4 me = sp4[n];
  float px = me.x, py = me.y, pz = me.z, sp = me.w;
  float bd[KK]; int bi[KK];
  #pragma unroll
  for (int s = 0; s < KK; ++s) { bd[s] = 1e30f; bi[s] = -1; }
  #pragma unroll 4
  for (int j = 0; j < 16; ++j) {
    int m = lane + (j << 6);
    float4 c = sp4[m];
    float dot = fmaf(px, c.x, fmaf(py, c.y, pz * c.z));
    float d = fmaf(-2.f, dot, sp + c.w);
    d = fmaxf(d, 0.f);
    if (d < bd[KK - 1]) {
      bd[KK - 1] = d; bi[KK - 1] = m;
      #pragma unroll
      for (int s = KK - 1; s >= 1; --s) {
        if (bd[s] < bd[s - 1]) {
          float td = bd[s]; bd[s] = bd[s - 1]; bd[s - 1] = td;
          int ti = bi[s]; bi[s] = bi[s - 1]; bi[s - 1] = ti;
        }
      }
    }
  }
  int* op = idx_out + ((size_t)b * NN + n) * KK;
  for (int s = 0; s < KK; ++s) {
    float d = bd[0]; int i = bi[0];
    #pragma unroll
    for (int off = 32; off > 0; off >>= 1) {
      float od = __shfl_xor(d, off, 64);
      int oi = __shfl_xor(i, off, 64);
      if (od < d || (od == d && oi < i)) { d = od; i = oi; }
    }
    if (bi[0] == i) {
      #pragma unroll
      for (int u = 0; u < KK - 1; ++u) { bd[u] = bd[u + 1]; bi[u] = bi[u + 1]; }
      bd[KK - 1] = 1e30f; bi[KK - 1] = -1;
    }
    if (lane == 0) op[s] = i;
  }
}

// -------- fused MLP per (b,n): 2 waves x 5 k's; array-parallel shuffle reductions ----
__global__ __launch_bounds__(128) void mlp_kernel(
    const float* __restrict__ Cat_uv, const float* __restrict__ lng, const float* __restrict__ lnb,
    const float* __restrict__ W2, const int* __restrict__ idxk, const float* __restrict__ q_pos,
    float* __restrict__ shp) {
  int bn = blockIdx.x;
  int b = bn >> 10;
  int tid = threadIdx.x;
  int wave = tid >> 6, lane = tid & 63;
  __shared__ int s_nb[KK];
  __shared__ float s_scale[3], s_lvp[KK][3];
  if (tid < KK) s_nb[tid] = idxk[(size_t)bn * KK + tid];
  __syncthreads();
  if (tid < 3) {
    float mx = -1e30f, mn = 1e30f;
    #pragma unroll
    for (int k2 = 0; k2 < KK; ++k2) {
      float v = q_pos[((size_t)b * NN + s_nb[k2]) * 3 + tid];
      mx = fmaxf(mx, v); mn = fminf(mn, v);
      s_lvp[k2][tid] = v;
    }
    s_scale[tid] = (mx - mn) * 0.5f;
  }
  __syncthreads();
  int kbase = wave * 5;
  float Vv[6], lg[6], lb[6], w2a[6], w2b[6], w2c[6];
  const float* Vrow = Cat_uv + (size_t)bn * (2 * CC) + CC;
  #pragma unroll
  for (int i = 0; i < 6; ++i) {
    int c = lane + (i << 6);
    Vv[i] = Vrow[c];
    lg[i] = lng[c]; lb[i] = lnb[c];
    w2a[i] = W2[c * 3 + 0]; w2b[i] = W2[c * 3 + 1]; w2c[i] = W2[c * 3 + 2];
  }
  // prefetch all 5 k's h values; 5-wide parallel reductions
  float hk[5][6];
  float sum[5];
  #pragma unroll
  for (int kk = 0; kk < 5; ++kk) {
    const float* Urow = Cat_uv + ((size_t)b * NN + s_nb[kbase + kk]) * (2 * CC);
    float s = 0.f;
    #pragma unroll
    for (int i = 0; i < 6; ++i) {
      hk[kk][i] = Urow[lane + (i << 6)] + Vv[i];
      s += hk[kk][i];
    }
    sum[kk] = s;
  }
  wave_sum_arr<5>(sum);
  float mu[5], var[5];
  #pragma unroll
  for (int kk = 0; kk < 5; ++kk) {
    mu[kk] = sum[kk] * (1.0f / CC);
    float v = 0.f;
    #pragma unroll
    for (int i = 0; i < 6; ++i) { float d = hk[kk][i] - mu[kk]; v += d * d; }
    var[kk] = v;
  }
  wave_sum_arr<5>(var);
  float o[15];
  #pragma unroll
  for (int kk = 0; kk < 5; ++kk) {
    float rstd = 1.0f / sqrtf(var[kk] * (1.0f / CC) + 1e-5f);
    float o0 = 0.f, o1 = 0.f, o2 = 0.f;
    #pragma unroll
    for (int i = 0; i < 6; ++i) {
      float x = (hk[kk][i] - mu[kk]) * rstd * lg[i] + lb[i];
      float g = 0.5f * x * (1.0f + erff(x * 0.70710678118654752440f));  // exact gelu
      o0 = fmaf(g, w2a[i], o0); o1 = fmaf(g, w2b[i], o1); o2 = fmaf(g, w2c[i], o2);
    }
    o[kk * 3 + 0] = o0; o[kk * 3 + 1] = o1; o[kk * 3 + 2] = o2;
  }
  wave_sum_arr<15>(o);
  if (lane == 0) {
    #pragma unroll
    for (int kk = 0; kk < 5; ++kk) {
      int k = kbase + kk;
      float* sp = shp + ((size_t)bn * KK + k) * 3;
      sp[0] = s_lvp[k][0] + tanhf(o[kk * 3 + 0]) * s_scale[0];
      sp[1] = s_lvp[k][1] + tanhf(o[kk * 3 + 1]) * s_scale[1];
      sp[2] = s_lvp[k][2] + tanhf(o[kk * 3 + 2]) * s_scale[2];
    }
  }
}

// ------- three_nn (f32): 4 pts/wave, float4 LDS, branchless top-3 --------------------
__global__ __launch_bounds__(256) void three_nn_kernel(
    const float* __restrict__ q_pos, const float* __restrict__ shp,
    float* __restrict__ w3, int* __restrict__ i3) {
  __shared__ float4 sp4[NN];
  int b = blockIdx.y;
  int t = threadIdx.x;
  const float* qp = q_pos + (size_t)b * NN * 3;
  for (int i = t; i < NN; i += 256) {
    float x = qp[i * 3 + 0], y = qp[i * 3 + 1], z = qp[i * 3 + 2];
    sp4[i] = (float4){x, y, z, x * x + y * y + z * z};
  }
  __syncthreads();
  int wave = t >> 6, lane = t & 63;
  for (int pp = 0; pp < 4; ++pp) {
    int p = blockIdx.x * 16 + wave * 4 + pp;
    const float* spnt = shp + ((size_t)b * NKK + p) * 3;
    float px = spnt[0], py = spnt[1], pz = spnt[2];
    float sp = fmaf(px, px, fmaf(py, py, pz * pz));
    float d0 = 1e30f, d1 = 1e30f, d2 = 1e30f;
    int i0 = -1, i1 = -1, i2 = -1;
    #pragma unroll 4
    for (int j = 0; j < 16; ++j) {
      int m = lane + (j << 6);
      float4 c = sp4[m];
      float dot = fmaf(px, c.x, fmaf(py, c.y, pz * c.z));
      float d = fmaf(-2.f, dot, sp + c.w);
      d = fmaxf(d, 0.f);
      bool c2 = d < d2, c1 = d < d1, c0 = d < d0;
      d2 = c1 ? d1 : (c2 ? d : d2);  i2 = c1 ? i1 : (c2 ? m : i2);
      d1 = c0 ? d0 : (c1 ? d : d1);  i1 = c0 ? i0 : (c1 ? m : i1);
      d0 = c0 ? d : d0;              i0 = c0 ? m : i0;
    }
    float wd[3]; int wi[3];
    #pragma unroll
    for (int s = 0; s < 3; ++s) {
      float d = d0; int i = i0;
      #pragma unroll
      for (int off = 32; off > 0; off >>= 1) {
        float od = __shfl_xor(d, off, 64);
        int oi = __shfl_xor(i, off, 64);
        if (od < d || (od == d && oi < i)) { d = od; i = oi; }
      }
      if (i0 == i) { d0 = d1; i0 = i1; d1 = d2; i1 = i2; d2 = 1e30f; i2 = -1; }
      wd[s] = d; wi[s] = i;
    }
    if (lane == 0) {
      float w0 = 1.f / (wd[0] + 1e-8f), w1 = 1.f / (wd[1] + 1e-8f), w2 = 1.f / (wd[2] + 1e-8f);
      float s = w0 + w1 + w2;
      float* wp = w3 + ((size_t)b * NKK + p) * 3;
      int* ip = i3 + ((size_t)b * NKK + p) * 3;
      wp[0] = w0 / s; wp[1] = w1 / s; wp[2] = w2 / s;
      ip[0] = wi[0]; ip[1] = wi[1]; ip[2] = wi[2];
    }
  }
}

// ------- final: 4 n per block, float4 cols ---------------------------------------
__global__ __launch_bounds__(384) void final_kernel(
    const float* __restrict__ Cat_pb,
    const float* __restrict__ w3, const int* __restrict__ i3,
    float* __restrict__ out) {
  int b = blockIdx.y;
  int t = threadIdx.x;
  __shared__ float sw[4][KK * 3];
  __shared__ int si[4][KK * 3];
  if (t < 4 * KK * 3) {
    int nl2 = t / (KK * 3), rr = t % (KK * 3);
    size_t base = ((size_t)b * NKK + ((size_t)blockIdx.x * 4 + nl2) * KK) * 3 + rr;
    sw[nl2][rr] = w3[base];
    si[nl2][rr] = i3[base];
  }
  __syncthreads();
  int nl = t / 96, c4 = (t % 96) * 4;
  int n = blockIdx.x * 4 + nl;
  size_t bn = (size_t)b * NN + n;
  const float* Pb = Cat_pb + (size_t)b * NN * (2 * CC);
  float4 base = *reinterpret_cast<const float4*>(Cat_pb + bn * (2 * CC) + CC + c4);
  float4 best = {-1e30f, -1e30f, -1e30f, -1e30f};
  #pragma unroll
  for (int k = 0; k < KK; ++k) {
    float4 acc = base;
    #pragma unroll
    for (int tt = 0; tt < 3; ++tt) {
      float wgt = sw[nl][k * 3 + tt];
      const float4 pv = *reinterpret_cast<const float4*>(Pb + (size_t)si[nl][k * 3 + tt] * (2 * CC) + c4);
      acc.x += wgt * pv.x; acc.y += wgt * pv.y; acc.z += wgt * pv.z; acc.w += wgt * pv.w;
    }
    acc.x = acc.x >= 0.f ? acc.x : 0.2f * acc.x;
    acc.y = acc.y >= 0.f ? acc.y : 0.2f * acc.y;
    acc.z = acc.z >= 0.f ? acc.z : 0.2f * acc.z;
    acc.w = acc.w >= 0.f ? acc.w : 0.2f * acc.w;
    best.x = fmaxf(best.x, acc.x); best.y = fmaxf(best.y, acc.y);
    best.z = fmaxf(best.z, acc.z); best.w = fmaxf(best.w, acc.w);
  }
  *reinterpret_cast<float4*>(out + bn * CC + c4) = best;
}

extern "C" void kernel_launch(void* const* d_in, const int* in_sizes, int n_in,
                              void* d_out, int out_size, void* d_ws, size_t ws_size,
                              hipStream_t stream) {
  (void)in_sizes; (void)n_in; (void)out_size; (void)ws_size;
  const float* q    = (const float*)d_in[0];
  const float* qpos = (const float*)d_in[1];
  const float* Wv   = (const float*)d_in[2];
  const float* bv   = (const float*)d_in[3];
  const float* W1   = (const float*)d_in[4];
  const float* b1   = (const float*)d_in[5];
  const float* lng  = (const float*)d_in[6];
  const float* lnb  = (const float*)d_in[7];
  const float* W2   = (const float*)d_in[8];
  const float* Wk   = (const float*)d_in[9];
  const float* bk   = (const float*)d_in[10];
  float* out = (float*)d_out;

  float* ws = (float*)d_ws;
  float* Cat_uv = ws; ws += (size_t)BB * NN * 2 * CC;   // [4096][768] U|V
  float* Cat_pb = ws; ws += (size_t)BB * NN * 2 * CC;   // [4096][768] P|Bse
  float* M1p = Cat_pb;                                   // alias: consumed before Cat_pb written
  float* bias_uv = ws; ws += 2 * CC;
  float* bias_pb = ws; ws += 2 * CC;
  float* shp = ws; ws += (size_t)BB * NKK * 3;
  float* w3  = ws; ws += (size_t)BB * NKK * 3;
  unsigned short* qh = (unsigned short*)ws;  ws += (size_t)BB * NN * CC / 2;
  unsigned short* ql = (unsigned short*)ws;  ws += (size_t)BB * NN * CC / 2;
  unsigned short* Wt = (unsigned short*)ws;  ws += (size_t)2 * CC * CC / 2;
  unsigned short* Buvh = (unsigned short*)ws; ws += (size_t)2 * CC * CC / 2;
  unsigned short* Buvl = (unsigned short*)ws; ws += (size_t)2 * CC * CC / 2;
  int* idxk = (int*)ws;
  int* i3   = idxk + (size_t)BB * NN * KK;

  // fused prep: cvt_split + pack_pb + biasprep
  prep_kernel<<<dim3(NB_CVT + NB_PB + 3), dim3(256), 0, stream>>>(
      q, W1, b1, bv, bk, Wk, qh, ql, Wt, bias_uv, bias_pb);
  // M1 partials (split-K=8), then pack+split into Buvh/Buvl
  gemm128_kernel<<<dim3(CC / 128, CC / 128, 8), dim3(256), 0, stream>>>(
      Wv, W1, M1p, nullptr, CC, CC, CC, 8);
  pack_uv_split_kernel<<<dim3(CC * 2 * CC / 256), dim3(256), 0, stream>>>(M1p, W1, Buvh, Buvl);
  // one dispatch: z=0 -> Cat_uv (bf16x2-split, ~f32 accuracy); z=1 -> Cat_pb (bf16)
  gemm_mfma_kernel<<<dim3(2 * CC / 128, BB * NN / 128, 2), dim3(256), 0, stream>>>(
      qh, ql, Buvh, Buvl, Wt, Cat_uv, Cat_pb, bias_uv, bias_pb);

  knn_kernel<<<dim3(NN / 4, BB), dim3(256), 0, stream>>>(qpos, idxk);
  mlp_kernel<<<dim3(BB * NN), dim3(128), 0, stream>>>(Cat_uv, lng, lnb, W2, idxk, qpos, shp);
  three_nn_kernel<<<dim3(NKK / 16, BB), dim3(256), 0, stream>>>(qpos, shp, w3, i3);
  final_kernel<<<dim3(NN / 4, BB), dim3(384), 0, stream>>>(Cat_pb, w3, i3, out);
}

// Round 6
// 161.351 us; speedup vs baseline: 1.5098x; 1.0370x over previous
//
#include <hip/hip_runtime.h>
#include <math.h>

#define BB 4
#define NN 1024
#define CC 384
#define KK 10
#define NKK (NN*KK)

typedef __attribute__((ext_vector_type(8))) short short8v;
typedef __attribute__((ext_vector_type(8))) unsigned short ushort8v;
typedef __attribute__((ext_vector_type(4))) float f32x4;

template <int NA>
__device__ __forceinline__ void wave_sum_arr(float* a) {
  #pragma unroll
  for (int off = 32; off > 0; off >>= 1) {
    float t[NA];
    #pragma unroll
    for (int u = 0; u < NA; ++u) t[u] = __shfl_xor(a[u], off, 64);
    #pragma unroll
    for (int u = 0; u < NA; ++u) a[u] += t[u];
  }
}

__device__ __forceinline__ unsigned short f2bf(float x) {
  unsigned int b = __float_as_uint(x);
  return (unsigned short)((b + 0x7fffu + ((b >> 16) & 1u)) >> 16);  // RNE
}
__device__ __forceinline__ float bf2f(unsigned short h) {
  return __uint_as_float(((unsigned int)h) << 16);
}

// ======== fused prep + M1 split-K GEMM, partitioned by blockIdx ========
// [0,NB_CVT): q->bf16 hi/lo | [NB_CVT,+NB_PB): Wk pack | +3: biases | +72: gemm128 M1
#define NB_CVT  (BB * NN * CC / 1024)        // 1536
#define NB_PB   (2 * CC * CC / 256)          // 1152
#define NB_PREP (NB_CVT + NB_PB + 3)
__global__ __launch_bounds__(256) void prep_gemm_kernel(
    const float* __restrict__ q,
    const float* __restrict__ W1, const float* __restrict__ b1,
    const float* __restrict__ bv, const float* __restrict__ bk,
    const float* __restrict__ Wk, const float* __restrict__ Wv,
    unsigned short* __restrict__ qh, unsigned short* __restrict__ ql,
    unsigned short* __restrict__ Wt,
    float* __restrict__ bias_uv, float* __restrict__ bias_pb,
    float* __restrict__ M1p) {
  int blk = blockIdx.x;
  int tid = threadIdx.x;
  if (blk < NB_CVT) {
    int i = (blk * 256 + tid) * 4;
    float4 v = *reinterpret_cast<const float4*>(q + i);
    float x[4] = {v.x, v.y, v.z, v.w};
    #pragma unroll
    for (int j = 0; j < 4; ++j) {
      unsigned short h = f2bf(x[j]);
      qh[i + j] = h;
      ql[i + j] = f2bf(x[j] - bf2f(h));
    }
    return;
  }
  if (blk < NB_CVT + NB_PB) {
    int idx = (blk - NB_CVT) * 256 + tid;    // 768*384
    int n = idx / CC, k = idx % CC;
    float v;
    if (n < CC) v = Wk[(size_t)k * CC + n];
    else        v = Wk[(size_t)CC * CC + k * CC + (n - CC)] - Wk[(size_t)k * CC + (n - CC)];
    Wt[(size_t)n * CC + k] = f2bf(v);
    return;
  }
  if (blk < NB_PREP) {
    int j = (blk - NB_CVT - NB_PB) * 256 + tid;
    if (j >= 2 * CC) return;
    if (j < CC) { bias_uv[j] = 0.f; bias_pb[j] = 0.f; }
    else {
      int c = j - CC;
      float s = b1[c];
      for (int i = 0; i < CC; ++i) s += bv[i] * W1[i * CC + c];
      bias_uv[j] = s;          // c1
      bias_pb[j] = bk[c];
    }
    return;
  }
  // ---- gemm128: M1p[z] = Wv @ W1_top (K-slice z), 72 blocks (3x3x8) ----
  {
    int r = blk - NB_PREP;
    int bx = r % 3, by = (r / 3) % 3, bz = r / 9;
    __shared__ float As[16][132];
    __shared__ float Bs[16][128];
    int tx = tid & 15, ty = tid >> 4;
    int row0 = by * 128, col0 = bx * 128;
    int k0 = bz * 48;
    float acc[8][8] = {};
    int arow = tid >> 2, akc = (tid & 3) << 2;
    int brow = tid >> 5, bcol = (tid & 31) << 2;
    for (int kt = k0; kt < k0 + 48; kt += 16) {
      #pragma unroll
      for (int h = 0; h < 2; ++h) {
        int rr = arow + 64 * h;
        float4 av = *reinterpret_cast<const float4*>(Wv + (size_t)(row0 + rr) * CC + kt + akc);
        As[akc + 0][rr] = av.x; As[akc + 1][rr] = av.y;
        As[akc + 2][rr] = av.z; As[akc + 3][rr] = av.w;
      }
      #pragma unroll
      for (int h = 0; h < 2; ++h) {
        int rr = brow + 8 * h;
        float4 bv4 = *reinterpret_cast<const float4*>(W1 + (size_t)(kt + rr) * CC + col0 + bcol);
        *reinterpret_cast<float4*>(&Bs[rr][bcol]) = bv4;
      }
      __syncthreads();
      #pragma unroll
      for (int kk = 0; kk < 16; ++kk) {
        float4 a0 = *reinterpret_cast<const float4*>(&As[kk][ty << 2]);
        float4 a1 = *reinterpret_cast<const float4*>(&As[kk][64 + (ty << 2)]);
        float4 b0 = *reinterpret_cast<const float4*>(&Bs[kk][tx << 2]);
        float4 b1 = *reinterpret_cast<const float4*>(&Bs[kk][64 + (tx << 2)]);
        float av_[8] = {a0.x, a0.y, a0.z, a0.w, a1.x, a1.y, a1.z, a1.w};
        float bv_[8] = {b0.x, b0.y, b0.z, b0.w, b1.x, b1.y, b1.z, b1.w};
        #pragma unroll
        for (int i = 0; i < 8; ++i)
          #pragma unroll
          for (int j = 0; j < 8; ++j) acc[i][j] += av_[i] * bv_[j];
      }
      __syncthreads();
    }
    float* Cz = M1p + (size_t)bz * CC * CC;
    #pragma unroll
    for (int i = 0; i < 8; ++i) {
      int row = row0 + (ty << 2) + (i & 3) + ((i & 4) << 4);
      if (row >= CC) continue;
      #pragma unroll
      for (int h = 0; h < 2; ++h) {
        int col = col0 + 64 * h + (tx << 2);
        if (col >= CC) continue;
        float4 rv;
        rv.x = acc[i][4 * h + 0]; rv.y = acc[i][4 * h + 1];
        rv.z = acc[i][4 * h + 2]; rv.w = acc[i][4 * h + 3];
        *reinterpret_cast<float4*>(Cz + (size_t)row * CC + col) = rv;
      }
    }
  }
}

// ------- Buv_t[n][k] = (n<384 ? M1[k][n] : W1_bot[k][n-384]) split hi/lo -------------
__global__ void pack_uv_split_kernel(const float* __restrict__ M1p, const float* __restrict__ W1,
                                     unsigned short* __restrict__ Buvh,
                                     unsigned short* __restrict__ Buvl) {
  int idx = blockIdx.x * 256 + threadIdx.x;   // 384*768, k-major for coalesced reads
  int k = idx / (2 * CC), n = idx % (2 * CC);
  float val;
  if (n < CC) {
    float s = 0.f;
    #pragma unroll
    for (int p = 0; p < 8; ++p) s += M1p[(size_t)p * CC * CC + (size_t)k * CC + n];
    val = s;
  } else {
    val = W1[(size_t)(CC + k) * CC + (n - CC)];
  }
  unsigned short h = f2bf(val);
  Buvh[(size_t)n * CC + k] = h;
  Buvl[(size_t)n * CC + k] = f2bf(val - bf2f(h));
}

// ------- merged MFMA GEMM: z=0: Cuv = q@Buv (bf16x2-split, 3 products)
//                           z=1: Cpb = q@Wt^T (bf16, 1 product) ------------------------
__global__ __launch_bounds__(256) void gemm_mfma_kernel(
    const unsigned short* __restrict__ qh, const unsigned short* __restrict__ ql,
    const unsigned short* __restrict__ Buvh, const unsigned short* __restrict__ Buvl,
    const unsigned short* __restrict__ Wt,
    float* __restrict__ Cuv, float* __restrict__ Cpb,
    const float* __restrict__ bias_uv, const float* __restrict__ bias_pb) {
  int path = blockIdx.z;                 // 0 = uv (split), 1 = pb
  const unsigned short* Bh = path ? Wt : Buvh;
  float* Cm = path ? Cpb : Cuv;
  const float* bias = path ? bias_pb : bias_uv;
  __shared__ unsigned short Ah[128 * 32], Alo[128 * 32];
  __shared__ unsigned short Bhs[128 * 32], Bls[128 * 32];
  int tid = threadIdx.x;
  int lane = tid & 63, w = tid >> 6;
  int m0 = blockIdx.y * 128, n0 = blockIdx.x * 128;
  f32x4 acc[4][4];
  #pragma unroll
  for (int i = 0; i < 4; ++i)
    #pragma unroll
    for (int j = 0; j < 4; ++j) acc[i][j] = (f32x4){0.f, 0.f, 0.f, 0.f};
  int rl = lane & 15, kg = lane >> 4;
  for (int k0 = 0; k0 < CC; k0 += 32) {
    #pragma unroll
    for (int j = 0; j < 2; ++j) {
      int id = tid + 256 * j;
      int r = id >> 2, s = id & 3;
      int sw = (s ^ (r & 3)) * 8;
      *reinterpret_cast<ushort8v*>(Ah + r * 32 + sw) =
          *reinterpret_cast<const ushort8v*>(qh + (size_t)(m0 + r) * CC + k0 + s * 8);
      *reinterpret_cast<ushort8v*>(Bhs + r * 32 + sw) =
          *reinterpret_cast<const ushort8v*>(Bh + (size_t)(n0 + r) * CC + k0 + s * 8);
      if (!path) {
        *reinterpret_cast<ushort8v*>(Alo + r * 32 + sw) =
            *reinterpret_cast<const ushort8v*>(ql + (size_t)(m0 + r) * CC + k0 + s * 8);
        *reinterpret_cast<ushort8v*>(Bls + r * 32 + sw) =
            *reinterpret_cast<const ushort8v*>(Buvl + (size_t)(n0 + r) * CC + k0 + s * 8);
      }
    }
    __syncthreads();
    short8v afh[4], bfh[4], afl[4], bfl[4];
    #pragma unroll
    for (int f = 0; f < 4; ++f) {
      int ar = (w & 1) * 64 + f * 16 + rl;
      int aof = ar * 32 + (kg ^ (ar & 3)) * 8;
      int br = (w >> 1) * 64 + f * 16 + rl;
      int bof = br * 32 + (kg ^ (br & 3)) * 8;
      afh[f] = *reinterpret_cast<const short8v*>(Ah + aof);
      bfh[f] = *reinterpret_cast<const short8v*>(Bhs + bof);
      if (!path) {
        afl[f] = *reinterpret_cast<const short8v*>(Alo + aof);
        bfl[f] = *reinterpret_cast<const short8v*>(Bls + bof);
      }
    }
    #pragma unroll
    for (int i = 0; i < 4; ++i) {
      #pragma unroll
      for (int j = 0; j < 4; ++j) {
        acc[i][j] = __builtin_amdgcn_mfma_f32_16x16x32_bf16(afh[i], bfh[j], acc[i][j], 0, 0, 0);
        if (!path) {
          acc[i][j] = __builtin_amdgcn_mfma_f32_16x16x32_bf16(afh[i], bfl[j], acc[i][j], 0, 0, 0);
          acc[i][j] = __builtin_amdgcn_mfma_f32_16x16x32_bf16(afl[i], bfh[j], acc[i][j], 0, 0, 0);
        }
      }
    }
    __syncthreads();
  }
  // C/D layout: col = lane&15, row = (lane>>4)*4 + reg
  #pragma unroll
  for (int i = 0; i < 4; ++i) {
    #pragma unroll
    for (int j = 0; j < 4; ++j) {
      int col = n0 + (w >> 1) * 64 + j * 16 + rl;
      float bcol_v = bias[col];
      #pragma unroll
      for (int r = 0; r < 4; ++r) {
        int row = m0 + (w & 1) * 64 + i * 16 + kg * 4 + r;
        Cm[(size_t)row * (2 * CC) + col] = acc[i][j][r] + bcol_v;
      }
    }
  }
}

// ======== fused tail: knn + bbox + MLP + three_nn + final, one block per (b,n) ========
__global__ __launch_bounds__(256) void tail_kernel(
    const float* __restrict__ Cat_uv, const float* __restrict__ Cat_pb,
    const float* __restrict__ lng, const float* __restrict__ lnb,
    const float* __restrict__ W2, const float* __restrict__ q_pos,
    float* __restrict__ out) {
  int bn = blockIdx.x;
  int b = bn >> 10, n = bn & (NN - 1);
  int tid = threadIdx.x;
  int wave = tid >> 6, lane = tid & 63;
  __shared__ float4 sp4[NN];
  __shared__ int s_nb[KK];
  __shared__ float s_scale[3], s_lvp[KK][3];
  __shared__ float s_shp[KK][3];
  __shared__ float s_w[KK][3];
  __shared__ int s_i[KK][3];

  // ---- stage positions (x,y,z,|p|^2) ----
  const float* qp = q_pos + (size_t)b * NN * 3;
  for (int i = tid; i < NN; i += 256) {
    float x = qp[i * 3 + 0], y = qp[i * 3 + 1], z = qp[i * 3 + 2];
    sp4[i] = (float4){x, y, z, x * x + y * y + z * z};
  }
  // prefetch per-channel params (independent of knn)
  float Vv[6], lg[6], lb[6], w2a[6], w2b[6], w2c[6];
  const float* Vrow = Cat_uv + (size_t)bn * (2 * CC) + CC;
  #pragma unroll
  for (int i = 0; i < 6; ++i) {
    int c = lane + (i << 6);
    Vv[i] = Vrow[c];
    lg[i] = lng[c]; lb[i] = lnb[c];
    w2a[i] = W2[c * 3 + 0]; w2b[i] = W2[c * 3 + 1]; w2c[i] = W2[c * 3 + 2];
  }
  __syncthreads();

  // ---- knn top-10 for query n (wave 0 only; verified stable) ----
  if (wave == 0) {
    float4 me = sp4[n];
    float px = me.x, py = me.y, pz = me.z, sp = me.w;
    float bd[KK]; int bi[KK];
    #pragma unroll
    for (int s = 0; s < KK; ++s) { bd[s] = 1e30f; bi[s] = -1; }
    #pragma unroll 4
    for (int j = 0; j < 16; ++j) {
      int m = lane + (j << 6);
      float4 c = sp4[m];
      float dot = fmaf(px, c.x, fmaf(py, c.y, pz * c.z));
      float d = fmaf(-2.f, dot, sp + c.w);
      d = fmaxf(d, 0.f);
      if (d < bd[KK - 1]) {
        bd[KK - 1] = d; bi[KK - 1] = m;
        #pragma unroll
        for (int s = KK - 1; s >= 1; --s) {
          if (bd[s] < bd[s - 1]) {
            float td = bd[s]; bd[s] = bd[s - 1]; bd[s - 1] = td;
            int ti = bi[s]; bi[s] = bi[s - 1]; bi[s - 1] = ti;
          }
        }
      }
    }
    for (int s = 0; s < KK; ++s) {
      float d = bd[0]; int i = bi[0];
      #pragma unroll
      for (int off = 32; off > 0; off >>= 1) {
        float od = __shfl_xor(d, off, 64);
        int oi = __shfl_xor(i, off, 64);
        if (od < d || (od == d && oi < i)) { d = od; i = oi; }
      }
      if (bi[0] == i) {
        #pragma unroll
        for (int u = 0; u < KK - 1; ++u) { bd[u] = bd[u + 1]; bi[u] = bi[u + 1]; }
        bd[KK - 1] = 1e30f; bi[KK - 1] = -1;
      }
      if (lane == 0) s_nb[s] = i;
    }
  }
  __syncthreads();

  // ---- bbox scale + neighbor positions (from LDS) ----
  if (tid < 3) {
    float mx = -1e30f, mn = 1e30f;
    #pragma unroll
    for (int k2 = 0; k2 < KK; ++k2) {
      const float* c = (const float*)&sp4[s_nb[k2]];
      float v = c[tid];
      mx = fmaxf(mx, v); mn = fminf(mn, v);
      s_lvp[k2][tid] = v;
    }
    s_scale[tid] = (mx - mn) * 0.5f;
  }
  __syncthreads();

  // ---- MLP: wave w handles ks [kb, kb+nk): 3,3,2,2 ----
  {
    int nk = (wave < 2) ? 3 : 2;
    int kb = (wave < 2) ? wave * 3 : 6 + (wave - 2) * 2;
    float hk[3][6];
    float sum[3];
    #pragma unroll
    for (int kk = 0; kk < 3; ++kk) {
      int k = kb + (kk < nk ? kk : nk - 1);
      const float* Urow = Cat_uv + ((size_t)b * NN + s_nb[k]) * (2 * CC);
      float s = 0.f;
      #pragma unroll
      for (int i = 0; i < 6; ++i) {
        hk[kk][i] = Urow[lane + (i << 6)] + Vv[i];
        s += hk[kk][i];
      }
      sum[kk] = s;
    }
    wave_sum_arr<3>(sum);
    float mu[3], var[3];
    #pragma unroll
    for (int kk = 0; kk < 3; ++kk) {
      mu[kk] = sum[kk] * (1.0f / CC);
      float v = 0.f;
      #pragma unroll
      for (int i = 0; i < 6; ++i) { float d = hk[kk][i] - mu[kk]; v += d * d; }
      var[kk] = v;
    }
    wave_sum_arr<3>(var);
    float o[9];
    #pragma unroll
    for (int kk = 0; kk < 3; ++kk) {
      float rstd = 1.0f / sqrtf(var[kk] * (1.0f / CC) + 1e-5f);
      float o0 = 0.f, o1 = 0.f, o2 = 0.f;
      #pragma unroll
      for (int i = 0; i < 6; ++i) {
        float x = (hk[kk][i] - mu[kk]) * rstd * lg[i] + lb[i];
        float g = 0.5f * x * (1.0f + erff(x * 0.70710678118654752440f));  // exact gelu
        o0 = fmaf(g, w2a[i], o0); o1 = fmaf(g, w2b[i], o1); o2 = fmaf(g, w2c[i], o2);
      }
      o[kk * 3 + 0] = o0; o[kk * 3 + 1] = o1; o[kk * 3 + 2] = o2;
    }
    wave_sum_arr<9>(o);
    if (lane == 0) {
      #pragma unroll
      for (int kk = 0; kk < 3; ++kk) {
        if (kk < nk) {
          int k = kb + kk;
          s_shp[k][0] = s_lvp[k][0] + tanhf(o[kk * 3 + 0]) * s_scale[0];
          s_shp[k][1] = s_lvp[k][1] + tanhf(o[kk * 3 + 1]) * s_scale[1];
          s_shp[k][2] = s_lvp[k][2] + tanhf(o[kk * 3 + 2]) * s_scale[2];
        }
      }
    }
  }
  __syncthreads();

  // ---- three_nn for the 10 shifted points; wave w takes p = w, w+4, w+8 ----
  for (int pi = 0; pi < 3; ++pi) {
    int p = wave + pi * 4;
    if (p >= KK) break;
    float px = s_shp[p][0], py = s_shp[p][1], pz = s_shp[p][2];
    float sp = fmaf(px, px, fmaf(py, py, pz * pz));
    float d0 = 1e30f, d1 = 1e30f, d2 = 1e30f;
    int i0 = -1, i1 = -1, i2 = -1;
    #pragma unroll 4
    for (int j = 0; j < 16; ++j) {
      int m = lane + (j << 6);
      float4 c = sp4[m];
      float dot = fmaf(px, c.x, fmaf(py, c.y, pz * c.z));
      float d = fmaf(-2.f, dot, sp + c.w);
      d = fmaxf(d, 0.f);
      bool c2 = d < d2, c1 = d < d1, c0 = d < d0;
      d2 = c1 ? d1 : (c2 ? d : d2);  i2 = c1 ? i1 : (c2 ? m : i2);
      d1 = c0 ? d0 : (c1 ? d : d1);  i1 = c0 ? i0 : (c1 ? m : i1);
      d0 = c0 ? d : d0;              i0 = c0 ? m : i0;
    }
    float wd[3]; int wi[3];
    #pragma unroll
    for (int s = 0; s < 3; ++s) {
      float d = d0; int i = i0;
      #pragma unroll
      for (int off = 32; off > 0; off >>= 1) {
        float od = __shfl_xor(d, off, 64);
        int oi = __shfl_xor(i, off, 64);
        if (od < d || (od == d && oi < i)) { d = od; i = oi; }
      }
      if (i0 == i) { d0 = d1; i0 = i1; d1 = d2; i1 = i2; d2 = 1e30f; i2 = -1; }
      wd[s] = d; wi[s] = i;
    }
    if (lane == 0) {
      float w0 = 1.f / (wd[0] + 1e-8f), w1 = 1.f / (wd[1] + 1e-8f), w2 = 1.f / (wd[2] + 1e-8f);
      float s = w0 + w1 + w2;
      s_w[p][0] = w0 / s; s_w[p][1] = w1 / s; s_w[p][2] = w2 / s;
      s_i[p][0] = wi[0];  s_i[p][1] = wi[1];  s_i[p][2] = wi[2];
    }
  }
  __syncthreads();

  // ---- final: out[b,n,c] = max_k lrelu( sum_t w*P[i,c] + Bse[bn,c] ) ----
  const float* Pb = Cat_pb + (size_t)b * NN * (2 * CC);
  const float* BseRow = Cat_pb + (size_t)bn * (2 * CC) + CC;
  for (int c = tid; c < CC; c += 256) {
    float base = BseRow[c];
    float best = -1e30f;
    #pragma unroll
    for (int k = 0; k < KK; ++k) {
      float acc = base;
      #pragma unroll
      for (int tt = 0; tt < 3; ++tt)
        acc = fmaf(s_w[k][tt], Pb[(size_t)s_i[k][tt] * (2 * CC) + c], acc);
      acc = acc >= 0.f ? acc : 0.2f * acc;
      best = fmaxf(best, acc);
    }
    out[(size_t)bn * CC + c] = best;
  }
}

extern "C" void kernel_launch(void* const* d_in, const int* in_sizes, int n_in,
                              void* d_out, int out_size, void* d_ws, size_t ws_size,
                              hipStream_t stream) {
  (void)in_sizes; (void)n_in; (void)out_size; (void)ws_size;
  const float* q    = (const float*)d_in[0];
  const float* qpos = (const float*)d_in[1];
  const float* Wv   = (const float*)d_in[2];
  const float* bv   = (const float*)d_in[3];
  const float* W1   = (const float*)d_in[4];
  const float* b1   = (const float*)d_in[5];
  const float* lng  = (const float*)d_in[6];
  const float* lnb  = (const float*)d_in[7];
  const float* W2   = (const float*)d_in[8];
  const float* Wk   = (const float*)d_in[9];
  const float* bk   = (const float*)d_in[10];
  float* out = (float*)d_out;

  float* ws = (float*)d_ws;
  float* Cat_uv = ws; ws += (size_t)BB * NN * 2 * CC;   // [4096][768] U|V
  float* Cat_pb = ws; ws += (size_t)BB * NN * 2 * CC;   // [4096][768] P|Bse
  float* M1p = Cat_pb;                                   // alias: consumed before Cat_pb written
  float* bias_uv = ws; ws += 2 * CC;
  float* bias_pb = ws; ws += 2 * CC;
  unsigned short* qh = (unsigned short*)ws;  ws += (size_t)BB * NN * CC / 2;
  unsigned short* ql = (unsigned short*)ws;  ws += (size_t)BB * NN * CC / 2;
  unsigned short* Wt = (unsigned short*)ws;  ws += (size_t)2 * CC * CC / 2;
  unsigned short* Buvh = (unsigned short*)ws; ws += (size_t)2 * CC * CC / 2;
  unsigned short* Buvl = (unsigned short*)ws; ws += (size_t)2 * CC * CC / 2;

  // 1) fused prep (cvt_split + Wk pack + biases) + M1 split-K GEMM
  prep_gemm_kernel<<<dim3(NB_PREP + 72), dim3(256), 0, stream>>>(
      q, W1, b1, bv, bk, Wk, Wv, qh, ql, Wt, bias_uv, bias_pb, M1p);
  // 2) reduce M1 partials + pack/split Buv
  pack_uv_split_kernel<<<dim3(CC * 2 * CC / 256), dim3(256), 0, stream>>>(M1p, W1, Buvh, Buvl);
  // 3) one dispatch: z=0 -> Cat_uv (bf16x2-split, ~f32 accuracy); z=1 -> Cat_pb (bf16)
  gemm_mfma_kernel<<<dim3(2 * CC / 128, BB * NN / 128, 2), dim3(256), 0, stream>>>(
      qh, ql, Buvh, Buvl, Wt, Cat_uv, Cat_pb, bias_uv, bias_pb);
  // 4) fused tail: knn + bbox + MLP + three_nn + final
  tail_kernel<<<dim3(BB * NN), dim3(256), 0, stream>>>(
      Cat_uv, Cat_pb, lng, lnb, W2, qpos, out);
}